// Round 14
// baseline (738.291 us; speedup 1.0000x reference)
//
#include <hip/hip_runtime.h>
#include <hip/hip_bf16.h>
#include <cstdint>
#include <cstddef>

// ---------------- problem constants ----------------
#define BATCH   2
#define SEQLEN  4096
#define DMODEL  2048
#define DINNER  4096
#define NHEADS  64
#define HEADDIM 64
#define DSTATE  64
#define CHUNK   64
#define NCHUNK  (SEQLEN/CHUNK)      // 64
#define DPROJ   8384
#define DPROJ_PAD 8448
#define MTOK    (BATCH*SEQLEN)      // 8192
#define RMS_EPS 1e-6f

typedef __hip_bfloat16 bf16;
typedef __attribute__((ext_vector_type(8))) short bf16x8;
typedef __attribute__((ext_vector_type(4))) float f32x4;

__device__ __forceinline__ float siluf(float x) { return x / (1.f + expf(-x)); }
__device__ __forceinline__ float to_f(float x) { return x; }
__device__ __forceinline__ float to_f(bf16 x) { return __bfloat162float(x); }
__device__ __forceinline__ float bf2f(short s) { bf16 h; *(short*)&h = s; return __bfloat162float(h); }
__device__ __forceinline__ void from_f(float& d, float x) { d = x; }
__device__ __forceinline__ void from_f(bf16& d, float x) { d = __float2bfloat16(x); }

__device__ __forceinline__ void gload16(const void* g, void* l) {
  __builtin_amdgcn_global_load_lds(
      (const __attribute__((address_space(1))) void*)g,
      (__attribute__((address_space(3))) void*)l, 16, 0, 0);
}

// ---------------- gemm_w16: 256x256 tile, 16 waves (round-12, best GEMM) -----
template <typename TC, int KT>
__global__ __launch_bounds__(1024, 4) void gemm_w16(
    const bf16* __restrict__ A, int lda,
    const bf16* __restrict__ BT, int ldb,
    TC* __restrict__ C, int ldc, int gx) {
  __shared__ __align__(16) bf16 As[4 * 8192];
  __shared__ __align__(16) bf16 Bs[4 * 8192];
  const int tid  = threadIdx.x;
  const int lane = tid & 63;
  const int w    = tid >> 6;
  const int wm   = w >> 2;
  const int wn   = w & 3;
  const int lr   = lane & 15, lg = lane >> 4;
  const int fo   = 8 * (lg ^ ((lr >> 1) & 3));

  int nwg = gridDim.x;
  int bid = (int)blockIdx.x;
  int idx = (bid & 7) * (nwg >> 3) + (bid >> 3);
  int spos = idx % (8 * gx);
  const int m0 = ((idx / (8 * gx)) * 8 + (spos & 7)) * 256;
  const int n0 = (spos >> 3) * 256;

  const int srow = tid >> 2;
  const int ce   = 8 * ((tid & 3) ^ ((tid >> 3) & 3));
  const bf16* pA = A  + (size_t)(m0 + srow) * lda + ce;
  const bf16* pB = BT + (size_t)(n0 + srow) * ldb + ce;
  const int wofs = w * 512;
  const int aRd = (wm * 64 + lr) * 32 + fo;
  const int bRd = (wn * 64 + lr) * 32 + fo;

#define STAGE_A(kt) gload16(pA + ((kt) << 5), As + (((kt) & 3) << 13) + wofs)
#define STAGE_B(kt) gload16(pB + ((kt) << 5), Bs + (((kt) & 3) << 13) + wofs)

  f32x4 acc[4][4];
#pragma unroll
  for (int m = 0; m < 4; ++m)
#pragma unroll
    for (int n = 0; n < 4; ++n) acc[m][n] = (f32x4){0.f, 0.f, 0.f, 0.f};

#define KBODY(T, DOSTAGE, VMC) do {                                          \
    const bf16* Ab = As + (((T) & 3) << 13);                                 \
    const bf16* Bb = Bs + (((T) & 3) << 13);                                 \
    if (DOSTAGE) { STAGE_A((T) + 3); STAGE_B((T) + 3); }                     \
    bf16x8 bfv[4], af[4];                                                    \
    _Pragma("unroll")                                                        \
    for (int n = 0; n < 4; ++n) bfv[n] = *(const bf16x8*)&Bb[bRd + n * 512]; \
    _Pragma("unroll")                                                        \
    for (int m = 0; m < 4; ++m) af[m] = *(const bf16x8*)&Ab[aRd + m * 512];  \
    asm volatile("s_waitcnt lgkmcnt(0)" ::: "memory");                       \
    __builtin_amdgcn_sched_barrier(0);                                       \
    __builtin_amdgcn_s_setprio(1);                                           \
    _Pragma("unroll")                                                        \
    for (int m = 0; m < 4; ++m)                                              \
      _Pragma("unroll")                                                      \
      for (int n = 0; n < 4; ++n)                                            \
        acc[m][n] = __builtin_amdgcn_mfma_f32_16x16x32_bf16(af[m], bfv[n], acc[m][n], 0, 0, 0); \
    __builtin_amdgcn_s_setprio(0);                                           \
    asm volatile("s_waitcnt vmcnt(" #VMC ")" ::: "memory");                  \
    __builtin_amdgcn_s_barrier();                                            \
    __builtin_amdgcn_sched_barrier(0);                                       \
  } while (0)

  STAGE_A(0); STAGE_B(0); STAGE_A(1); STAGE_B(1); STAGE_A(2); STAGE_B(2);
  asm volatile("s_waitcnt vmcnt(4)" ::: "memory");
  __builtin_amdgcn_s_barrier();
  __builtin_amdgcn_sched_barrier(0);

#pragma unroll 4
  for (int t = 0; t < KT - 3; ++t) KBODY(t, true, 4);
  KBODY(KT - 3, false, 2);
  KBODY(KT - 2, false, 0);
  KBODY(KT - 1, false, 0);
#undef KBODY
#undef STAGE_A
#undef STAGE_B

  if constexpr (__is_same(TC, bf16)) {
    bf16* Ws = (w < 8 ? As : Bs) + (w & 7) * 4096;
#pragma unroll
    for (int m = 0; m < 4; ++m)
#pragma unroll
      for (int n = 0; n < 4; ++n)
#pragma unroll
        for (int reg = 0; reg < 4; ++reg) {
          int row = m * 16 + lg * 4 + reg;
          int slot = (n * 2 + (lr >> 3)) ^ (row & 7);
          Ws[row * 64 + slot * 8 + (lr & 7)] = __float2bfloat16(acc[m][n][reg]);
        }
    asm volatile("s_waitcnt lgkmcnt(0)" ::: "memory");
#pragma unroll
    for (int i = 0; i < 8; ++i) {
      int row = i * 8 + (lane >> 3);
      bf16x8 v = *(const bf16x8*)&Ws[row * 64 + ((lane & 7) ^ (lane >> 3)) * 8];
      int gcol = n0 + wn * 64 + (lane & 7) * 8;
      *(bf16x8*)&((bf16*)C)[(size_t)(m0 + wm * 64 + row) * ldc + gcol] = v;
    }
  } else {
#pragma unroll
    for (int m = 0; m < 4; ++m)
#pragma unroll
      for (int n = 0; n < 4; ++n) {
        int col = n0 + wn * 64 + n * 16 + lr;
        size_t rbase = (size_t)(m0 + wm * 64 + m * 16 + lg * 4);
#pragma unroll
        for (int reg = 0; reg < 4; ++reg)
          from_f(C[(rbase + reg) * ldc + col], acc[m][n][reg]);
      }
  }
}

// ---------------- round-4 128x128 MFMA GEMM — for the narrow BCdt slice ------
template <typename TC, bool MASK>
__global__ __launch_bounds__(256) void gemm_mfma(
    const bf16* __restrict__ A, int lda,
    const bf16* __restrict__ BT, int ldb,
    TC* __restrict__ C, int ldc, int Kdim, int Nvalid) {
  __shared__ __align__(16) bf16 As[128 * 32];
  __shared__ __align__(16) bf16 Bs[128 * 32];
  const int tid  = threadIdx.x;
  const int lane = tid & 63;
  const int w    = tid >> 6;
  const int m0 = blockIdx.y * 128;
  const int n0 = blockIdx.x * 128;

  const int rs0 = w * 32 + (lane >> 2);
  const int ce  = 8 * ((lane & 3) ^ ((lane >> 2) & 3));
  const int fo  = 8 * ((lane >> 4) ^ (lane & 3));
  const int lr  = lane & 15, lg = lane >> 4;
  const int wr = w >> 1, wc = w & 1;

  f32x4 acc[4][4];
#pragma unroll
  for (int m = 0; m < 4; ++m)
#pragma unroll
    for (int n = 0; n < 4; ++n) acc[m][n] = (f32x4){0.f, 0.f, 0.f, 0.f};

  const size_t arow0 = (size_t)(m0 + rs0) * lda;
  const size_t arow1 = (size_t)(m0 + rs0 + 16) * lda;
  const size_t brow0 = (size_t)(n0 + rs0) * ldb;
  const size_t brow1 = (size_t)(n0 + rs0 + 16) * ldb;
  bf16* lA0 = &As[(w * 2 + 0) * 512];
  bf16* lA1 = &As[(w * 2 + 1) * 512];
  bf16* lB0 = &Bs[(w * 2 + 0) * 512];
  bf16* lB1 = &Bs[(w * 2 + 1) * 512];

  for (int k0 = 0; k0 < Kdim; k0 += 32) {
    __syncthreads();
    gload16(A + arow0 + k0 + ce, lA0);
    gload16(A + arow1 + k0 + ce, lA1);
    gload16(BT + brow0 + k0 + ce, lB0);
    gload16(BT + brow1 + k0 + ce, lB1);
    __syncthreads();
    bf16x8 af[4], bfr[4];
#pragma unroll
    for (int m = 0; m < 4; ++m)
      af[m] = *(const bf16x8*)&As[(wr * 64 + m * 16 + lr) * 32 + fo];
#pragma unroll
    for (int n = 0; n < 4; ++n)
      bfr[n] = *(const bf16x8*)&Bs[(wc * 64 + n * 16 + lr) * 32 + fo];
#pragma unroll
    for (int m = 0; m < 4; ++m)
#pragma unroll
      for (int n = 0; n < 4; ++n)
        acc[m][n] = __builtin_amdgcn_mfma_f32_16x16x32_bf16(af[m], bfr[n], acc[m][n], 0, 0, 0);
  }

#pragma unroll
  for (int m = 0; m < 4; ++m)
#pragma unroll
    for (int n = 0; n < 4; ++n) {
      int col = n0 + wc * 64 + n * 16 + lr;
      if (MASK && col >= Nvalid) continue;
      size_t rbase = (size_t)(m0 + wr * 64 + m * 16 + lg * 4);
#pragma unroll
      for (int reg = 0; reg < 4; ++reg)
        from_f(C[(rbase + reg) * ldc + col], acc[m][n][reg]);
    }
}

// ---------------- cast fp32 -> bf16 (4/thread) ----------------
__global__ __launch_bounds__(256) void cast_bf16_kernel(
    const float* __restrict__ x, bf16* __restrict__ y) {
  size_t i = ((size_t)blockIdx.x * 256 + threadIdx.x) * 4;
  float4 v = *(const float4*)(x + i);
  y[i + 0] = __float2bfloat16(v.x);
  y[i + 1] = __float2bfloat16(v.y);
  y[i + 2] = __float2bfloat16(v.z);
  y[i + 3] = __float2bfloat16(v.w);
}

// ---------------- transpose + cast: WT[Npad][K] = W[K][N]^T ----------------
__global__ __launch_bounds__(256) void transpose_cast_kernel(
    const float* __restrict__ W, bf16* __restrict__ WT, int N, int K) {
  __shared__ float t[32][33];
  int n0 = blockIdx.x * 32, k0 = blockIdx.y * 32;
  int tx = threadIdx.x & 31, ty = threadIdx.x >> 5;
#pragma unroll
  for (int i = 0; i < 4; ++i) {
    int n = n0 + tx;
    t[ty + i * 8][tx] = (n < N) ? W[(size_t)(k0 + ty + i * 8) * N + n] : 0.f;
  }
  __syncthreads();
#pragma unroll
  for (int i = 0; i < 4; ++i) {
    int nn = ty + i * 8;
    WT[(size_t)(n0 + nn) * K + k0 + tx] = __float2bfloat16(t[tx][nn]);
  }
}

// ---------------- depthwise causal conv1d (K=4) + SiLU, 4 tokens/thread ------
__global__ __launch_bounds__(256) void conv_silu_kernel(
    const bf16* __restrict__ zx, const float* __restrict__ cw,
    const float* __restrict__ cb, bf16* __restrict__ xc) {
  int idx = blockIdx.x * 256 + threadIdx.x;
  int d8 = (idx & 511) * 8;
  int g = idx >> 9;
  int m0 = g * 4;
  int l0 = m0 & (SEQLEN - 1);
  int b = m0 >> 12;
  bf16x8 rows[7];
  bf16x8 zvec;
#pragma unroll
  for (int j = 0; j < 8; ++j) zvec[j] = 0;
#pragma unroll
  for (int r = 0; r < 7; ++r) {
    int li = l0 - 3 + r;
    rows[r] = (li >= 0)
        ? *(const bf16x8*)&zx[(size_t)(b * SEQLEN + li) * DPROJ + DINNER + d8]
        : zvec;
  }
  float cwv[4][8], cbv[8];
#pragma unroll
  for (int k = 0; k < 4; ++k) {
    float4 a = *(const float4*)(cw + k * DINNER + d8);
    float4 bb = *(const float4*)(cw + k * DINNER + d8 + 4);
    cwv[k][0] = a.x; cwv[k][1] = a.y; cwv[k][2] = a.z; cwv[k][3] = a.w;
    cwv[k][4] = bb.x; cwv[k][5] = bb.y; cwv[k][6] = bb.z; cwv[k][7] = bb.w;
  }
  {
    float4 a = *(const float4*)(cb + d8);
    float4 bb = *(const float4*)(cb + d8 + 4);
    cbv[0] = a.x; cbv[1] = a.y; cbv[2] = a.z; cbv[3] = a.w;
    cbv[4] = bb.x; cbv[5] = bb.y; cbv[6] = bb.z; cbv[7] = bb.w;
  }
#pragma unroll
  for (int j = 0; j < 4; ++j) {
    float acc[8];
#pragma unroll
    for (int e = 0; e < 8; ++e) acc[e] = cbv[e];
#pragma unroll
    for (int k = 0; k < 4; ++k)
#pragma unroll
      for (int e = 0; e < 8; ++e) acc[e] += bf2f(rows[j + k][e]) * cwv[k][e];
    bf16x8 o;
#pragma unroll
    for (int e = 0; e < 8; ++e) { bf16 h = __float2bfloat16(siluf(acc[e])); o[e] = *(short*)&h; }
    *(bf16x8*)&xc[(size_t)(m0 + j) * DINNER + d8] = o;
  }
}

// ---------------- fused B/C elu+1 + log-decay + per-chunk cumsum --------------
__global__ __launch_bounds__(256) void prep_cumsum_kernel(
    const bf16* __restrict__ zx, const float* __restrict__ A_log,
    const float* __restrict__ dt_bias, bf16* __restrict__ Bmb,
    bf16* __restrict__ Cmb, float* __restrict__ cs) {
  int bid = blockIdx.x;            // b*64 + c
  int c = bid & 63, b = bid >> 6;
  int m0 = b * SEQLEN + c * CHUNK;
  int tid = threadIdx.x;
  int s = tid >> 2, grp = (tid & 3) * 16;
  __shared__ float laT[64 * 65];
  __shared__ float segs[4][64];
  const bf16* row = zx + (size_t)(m0 + s) * DPROJ + 2 * DINNER;
  {
    union { bf16x8 v[2]; bf16 hh[16]; } u, o;
    u.v[0] = *(const bf16x8*)&row[grp];
    u.v[1] = *(const bf16x8*)&row[grp + 8];
#pragma unroll
    for (int i = 0; i < 16; ++i) {
      float bv = to_f(u.hh[i]);
      from_f(o.hh[i], bv > 0.f ? bv + 1.f : expf(bv));
    }
    *(bf16x8*)&Bmb[(size_t)(m0 + s) * 64 + grp] = o.v[0];
    *(bf16x8*)&Bmb[(size_t)(m0 + s) * 64 + grp + 8] = o.v[1];
    u.v[0] = *(const bf16x8*)&row[64 + grp];
    u.v[1] = *(const bf16x8*)&row[64 + grp + 8];
#pragma unroll
    for (int i = 0; i < 16; ++i) {
      float cv = to_f(u.hh[i]);
      from_f(o.hh[i], cv > 0.f ? cv + 1.f : expf(cv));
    }
    *(bf16x8*)&Cmb[(size_t)(m0 + s) * 64 + grp] = o.v[0];
    *(bf16x8*)&Cmb[(size_t)(m0 + s) * 64 + grp + 8] = o.v[1];
    u.v[0] = *(const bf16x8*)&row[128 + grp];
    u.v[1] = *(const bf16x8*)&row[128 + grp + 8];
#pragma unroll
    for (int i = 0; i < 16; ++i) {
      int j = grp + i;
      float dtl = to_f(u.hh[i]) + dt_bias[j];
      float dt = dtl > 20.f ? dtl : log1pf(expf(dtl));
      laT[j * 65 + s] = -dt * expf(A_log[j]);
    }
  }
  __syncthreads();
  int j = tid & 63, sg = tid >> 6;
  float p = 0.f;
#pragma unroll
  for (int i = 0; i < 16; ++i) p += laT[j * 65 + sg * 16 + i];
  segs[sg][j] = p;
  __syncthreads();
  float off = (sg > 0 ? segs[0][j] : 0.f) + (sg > 1 ? segs[1][j] : 0.f) +
              (sg > 2 ? segs[2][j] : 0.f);
  float acc = off;
#pragma unroll
  for (int i = 0; i < 16; ++i) {
    acc += laT[j * 65 + sg * 16 + i];
    cs[(size_t)(m0 + sg * 16 + i) * 64 + j] = acc;
  }
}

// ---------------- fused SSD: states + inter-chunk scan + chunk output --------
// One block per (b, h, p-half); 256 thr = 4 waves; walks 64 chunks serially.
// Running state hT[32p][64n] lives in MFMA accumulators (2 f32x4/lane/wave:
// wave w owns p-tile pt=w&1, n-half nh=w>>1) and is mirrored to LDS (bf16)
// each chunk for the y_inter MFMA B-operand.  Eliminates the st tensor
// (3x 64 MiB HBM round-trips) and two kernel launches.
__global__ __launch_bounds__(256, 2) void ssd_fused(
    const bf16* __restrict__ Bmb, const bf16* __restrict__ Cmb,
    const bf16* __restrict__ xc, const float* __restrict__ cs,
    const float* __restrict__ Dp, bf16* __restrict__ zx) {
  int bid = blockIdx.x;            // b*128 + h*2 + ph
  int ph = bid & 1, h = (bid >> 1) & 63, b = bid >> 7;
  int tid = threadIdx.x, lane = tid & 63, w = tid >> 6;
  int lr = lane & 15, lg = lane >> 4;
  int pt = w & 1, nh = w >> 1;     // state ownership: p-tile, n-half
  __shared__ bf16 qL[64 * 72];     // q[s][n]
  __shared__ bf16 kL[64 * 72];     // k[t][n]
  __shared__ bf16 kscL[64 * 72];   // ksc^T [n][s]
  __shared__ bf16 B2[32 * 136];    // [p][ t(0..63) | 64+n(0..63) = hT ]
  __shared__ bf16 A2[64 * 136];    // [s][ att t | 64+qsc n ]; reused for y
  __shared__ float csl[64];
  int s4 = tid >> 2, c16 = (tid & 3) * 16, pg = (tid & 3) * 8;
  float Dh = Dp[h];

  // zero hT (B2 cols 64..127)
  {
    int pr = tid >> 3, c8 = (tid & 7) * 8;
    bf16x8 z;
#pragma unroll
    for (int j = 0; j < 8; ++j) z[j] = 0;
    *(bf16x8*)&B2[pr * 136 + 64 + c8] = z;
  }
  f32x4 acc_h[2];
  acc_h[0] = (f32x4){0.f, 0.f, 0.f, 0.f};
  acc_h[1] = (f32x4){0.f, 0.f, 0.f, 0.f};

  for (int c = 0; c < NCHUNK; ++c) {
    int m0 = b * SEQLEN + c * CHUNK;
    // ---- S1: stage q, k, ksc^T, vT(B2 t-cols), csl ----
    if (tid < 64) csl[tid] = cs[(size_t)(m0 + tid) * 64 + h];
    {
      const bf16x8* pq = (const bf16x8*)&Cmb[(size_t)(m0 + s4) * 64 + c16];
      *(bf16x8*)&qL[s4 * 72 + c16] = pq[0];
      *(bf16x8*)&qL[s4 * 72 + c16 + 8] = pq[1];
      union { bf16x8 v[2]; bf16 hh[16]; } u;
      const bf16x8* pk = (const bf16x8*)&Bmb[(size_t)(m0 + s4) * 64 + c16];
      u.v[0] = pk[0]; u.v[1] = pk[1];
      *(bf16x8*)&kL[s4 * 72 + c16] = u.v[0];
      *(bf16x8*)&kL[s4 * 72 + c16 + 8] = u.v[1];
      float cstot = cs[(size_t)(m0 + 63) * 64 + h];
      float ws = expf(cstot - cs[(size_t)(m0 + s4) * 64 + h]);
#pragma unroll
      for (int i = 0; i < 16; ++i)
        kscL[(c16 + i) * 72 + s4] = __float2bfloat16(to_f(u.hh[i]) * ws);
      union { bf16x8 v; bf16 hh[8]; } uv;
      uv.v = *(const bf16x8*)&xc[(size_t)(m0 + s4) * DINNER + h * 64 + ph * 32 + pg];
#pragma unroll
      for (int i = 0; i < 8; ++i) B2[(pg + i) * 136 + s4] = uv.hh[i];
    }
    __syncthreads();
    // ---- S2: att = q @ k^T (wave rows [w*16, w*16+16)) ----
    f32x4 acc1[4];
#pragma unroll
    for (int ct = 0; ct < 4; ++ct) acc1[ct] = (f32x4){0.f, 0.f, 0.f, 0.f};
#pragma unroll
    for (int ks = 0; ks < 2; ++ks) {
      bf16x8 af = *(const bf16x8*)&qL[(w * 16 + lr) * 72 + ks * 32 + lg * 8];
#pragma unroll
      for (int ct = 0; ct < 4; ++ct) {
        bf16x8 bf_ = *(const bf16x8*)&kL[(ct * 16 + lr) * 72 + ks * 32 + lg * 8];
        acc1[ct] = __builtin_amdgcn_mfma_f32_16x16x32_bf16(af, bf_, acc1[ct], 0, 0, 0);
      }
    }
    // ---- S3: A2 = [att (masked+decayed) | qsc] ----
    {
      float es = expf(csl[s4]);
      union { bf16x8 v[2]; bf16 hh[16]; } u;
      const bf16x8* pq = (const bf16x8*)&qL[s4 * 72 + c16];
      u.v[0] = pq[0]; u.v[1] = pq[1];
#pragma unroll
      for (int i = 0; i < 16; ++i) u.hh[i] = __float2bfloat16(to_f(u.hh[i]) * es);
      *(bf16x8*)&A2[s4 * 136 + 64 + c16] = u.v[0];
      *(bf16x8*)&A2[s4 * 136 + 64 + c16 + 8] = u.v[1];
    }
#pragma unroll
    for (int ct = 0; ct < 4; ++ct) {
      int t = ct * 16 + lr;
#pragma unroll
      for (int r = 0; r < 4; ++r) {
        int s = w * 16 + lg * 4 + r;
        float val = (t <= s) ? acc1[ct][r] * expf(csl[s] - csl[t]) : 0.f;
        A2[s * 136 + t] = __float2bfloat16(val);
      }
    }
    __syncthreads();
    // ---- S4: y = A2 @ B2^T (K=128, N=32), seeded with D*v ----
    f32x4 acc2[2];
#pragma unroll
    for (int ct = 0; ct < 2; ++ct) {
      int p = ct * 16 + lr;
#pragma unroll
      for (int r = 0; r < 4; ++r)
        acc2[ct][r] = Dh * to_f(B2[p * 136 + (w * 16 + lg * 4 + r)]);
    }
#pragma unroll
    for (int ks = 0; ks < 4; ++ks) {
      bf16x8 af = *(const bf16x8*)&A2[(w * 16 + lr) * 136 + ks * 32 + lg * 8];
#pragma unroll
      for (int ct = 0; ct < 2; ++ct) {
        bf16x8 bf_ = *(const bf16x8*)&B2[(ct * 16 + lr) * 136 + ks * 32 + lg * 8];
        acc2[ct] = __builtin_amdgcn_mfma_f32_16x16x32_bf16(af, bf_, acc2[ct], 0, 0, 0);
      }
    }
    // ---- S5: state update hT = dtot*hT + vT @ ksc ----
    {
      float dtot = expf(csl[63]);
#pragma unroll
      for (int ct = 0; ct < 2; ++ct)
#pragma unroll
        for (int r = 0; r < 4; ++r) acc_h[ct][r] *= dtot;
#pragma unroll
      for (int ks = 0; ks < 2; ++ks) {
        bf16x8 af = *(const bf16x8*)&B2[(pt * 16 + lr) * 136 + ks * 32 + lg * 8];
#pragma unroll
        for (int ct = 0; ct < 2; ++ct) {
          bf16x8 bf_ = *(const bf16x8*)&kscL[(nh * 32 + ct * 16 + lr) * 72 + ks * 32 + lg * 8];
          acc_h[ct] = __builtin_amdgcn_mfma_f32_16x16x32_bf16(af, bf_, acc_h[ct], 0, 0, 0);
        }
      }
    }
    __syncthreads();   // all S4 reads of B2-h / A2 done
    // ---- S6: write hT -> B2 h-part; y -> A2 cols 0..31 ----
#pragma unroll
    for (int ct = 0; ct < 2; ++ct)
#pragma unroll
      for (int r = 0; r < 4; ++r) {
        B2[(pt * 16 + lg * 4 + r) * 136 + 64 + nh * 32 + ct * 16 + lr] =
            __float2bfloat16(acc_h[ct][r]);
        A2[(w * 16 + lg * 4 + r) * 136 + ct * 16 + lr] = __float2bfloat16(acc2[ct][r]);
      }
    __syncthreads();
    // ---- S7: vector store y ----
    {
      bf16x8 yv = *(const bf16x8*)&A2[s4 * 136 + pg];
      *(bf16x8*)&zx[(size_t)(m0 + s4) * DPROJ + DINNER + h * 64 + ph * 32 + pg] = yv;
    }
  }
}

// ---------------- RMSNorm over 4096 + silu(z) gate, bf16x8 ----------------
__global__ __launch_bounds__(256) void rmsnorm_gate_kernel(
    bf16* __restrict__ zx, const float* __restrict__ scale) {
  int m = blockIdx.x;
  int tid = threadIdx.x;
  bf16* row = zx + (size_t)m * DPROJ;
  float vals[16];
  float ss = 0.f;
#pragma unroll
  for (int g = 0; g < 2; ++g) {
    int d8 = (tid + g * 256) * 8;
    bf16x8 yv = *(const bf16x8*)&row[DINNER + d8];
#pragma unroll
    for (int j = 0; j < 8; ++j) {
      float y = bf2f(yv[j]);
      vals[g * 8 + j] = y;
      ss += y * y;
    }
  }
#pragma unroll
  for (int off = 32; off > 0; off >>= 1) ss += __shfl_down(ss, off, 64);
  __shared__ float red[4];
  if ((tid & 63) == 0) red[tid >> 6] = ss;
  __syncthreads();
  float tot = red[0] + red[1] + red[2] + red[3];
  float inv = rsqrtf(tot / (float)DINNER + RMS_EPS);
#pragma unroll
  for (int g = 0; g < 2; ++g) {
    int d8 = (tid + g * 256) * 8;
    bf16x8 zv = *(const bf16x8*)&row[d8];
    const float* sc = scale + d8;
    bf16x8 o;
#pragma unroll
    for (int j = 0; j < 8; ++j) {
      bf16 hh = __float2bfloat16(vals[g * 8 + j] * inv * sc[j] * siluf(bf2f(zv[j])));
      o[j] = *(short*)&hh;
    }
    *(bf16x8*)&row[DINNER + d8] = o;
  }
}

// ---------------- launch ----------------
extern "C" void kernel_launch(void* const* d_in, const int* in_sizes, int n_in,
                              void* d_out, int out_size, void* d_ws, size_t ws_size,
                              hipStream_t stream) {
  const float* u       = (const float*)d_in[0];
  const float* Win     = (const float*)d_in[1];
  const float* cw      = (const float*)d_in[2];
  const float* cb      = (const float*)d_in[3];
  const float* A_log   = (const float*)d_in[4];
  const float* dt_bias = (const float*)d_in[5];
  const float* Dp      = (const float*)d_in[6];
  const float* nscale  = (const float*)d_in[7];
  const float* Wout    = (const float*)d_in[8];
  float* out = (float*)d_out;

  bf16* zx = (bf16*)d_ws;
  bf16* xc = zx + (size_t)MTOK * DPROJ;
  bf16* ub = xc;                                  // overlay: ub dead before xc written
  bf16* wT = xc + (size_t)MTOK * DINNER;
  bf16* Bmb = wT + (size_t)DPROJ_PAD * DMODEL;
  bf16* Cmb = Bmb + (size_t)MTOK * 64;
  float* cs = (float*)(Cmb + (size_t)MTOK * 64);

  cast_bf16_kernel<<<(MTOK * DMODEL) / (256 * 4), 256, 0, stream>>>(u, ub);
  transpose_cast_kernel<<<dim3(DPROJ_PAD / 32, DMODEL / 32), 256, 0, stream>>>(Win, wT, DPROJ, DMODEL);
  // 1a) in-projection z|x columns: N=8192, 16-wave kernel, grid 1024
  gemm_w16<bf16, DMODEL / 32><<<(2 * DINNER / 256) * (MTOK / 256), 1024, 0, stream>>>(
      ub, DMODEL, wT, DMODEL, zx, DPROJ, 2 * DINNER / 256);
  // 1b) in-projection BCdt columns: N=192 (pad 256), 128x128 kernel
  gemm_mfma<bf16, true><<<dim3(2, MTOK / 128), 256, 0, stream>>>(
      ub, DMODEL, wT + (size_t)(2 * DINNER) * DMODEL, DMODEL,
      zx + 2 * DINNER, DPROJ, DMODEL, 192);
  transpose_cast_kernel<<<dim3(DMODEL / 32, DINNER / 32), 256, 0, stream>>>(Wout, wT, DMODEL, DINNER);
  conv_silu_kernel<<<(MTOK / 4) * 512 / 256, 256, 0, stream>>>(zx, cw, cb, xc);
  prep_cumsum_kernel<<<BATCH * NCHUNK, 256, 0, stream>>>(zx, A_log, dt_bias, Bmb, Cmb, cs);
  // fused SSD: states + scan + chunk output (one resident kernel, 256 blocks)
  ssd_fused<<<BATCH * NHEADS * 2, 256, 0, stream>>>(Bmb, Cmb, xc, cs, Dp, zx);
  rmsnorm_gate_kernel<<<MTOK, 256, 0, stream>>>(zx, nscale);
  // 9) out-projection: 16-wave kernel, float out, grid 256, KT=128
  gemm_w16<float, DINNER / 32><<<(DMODEL / 256) * (MTOK / 256), 1024, 0, stream>>>(
      zx + DINNER, DPROJ, wT, DINNER, out, DMODEL, DMODEL / 256);
}

// Round 15
// 643.418 us; speedup vs baseline: 1.1475x; 1.1475x over previous
//
#include <hip/hip_runtime.h>
#include <hip/hip_bf16.h>
#include <cstdint>
#include <cstddef>

// ---------------- problem constants ----------------
#define BATCH   2
#define SEQLEN  4096
#define DMODEL  2048
#define DINNER  4096
#define NHEADS  64
#define HEADDIM 64
#define DSTATE  64
#define CHUNK   64
#define NCHUNK  (SEQLEN/CHUNK)      // 64
#define DPROJ   8384
#define DPROJ_PAD 8448
#define MTOK    (BATCH*SEQLEN)      // 8192
#define RMS_EPS 1e-6f

typedef __hip_bfloat16 bf16;
typedef __attribute__((ext_vector_type(8))) short bf16x8;
typedef __attribute__((ext_vector_type(4))) float f32x4;

__device__ __forceinline__ float siluf(float x) { return x / (1.f + expf(-x)); }
__device__ __forceinline__ float to_f(float x) { return x; }
__device__ __forceinline__ float to_f(bf16 x) { return __bfloat162float(x); }
__device__ __forceinline__ float bf2f(short s) { bf16 h; *(short*)&h = s; return __bfloat162float(h); }
__device__ __forceinline__ void from_f(float& d, float x) { d = x; }
__device__ __forceinline__ void from_f(bf16& d, float x) { d = __float2bfloat16(x); }

__device__ __forceinline__ void gload16(const void* g, void* l) {
  __builtin_amdgcn_global_load_lds(
      (const __attribute__((address_space(1))) void*)g,
      (__attribute__((address_space(3))) void*)l, 16, 0, 0);
}

// ---------------- gemm_w16: 256x256 tile, 16 waves (round-12, best GEMM) -----
template <typename TC, int KT>
__global__ __launch_bounds__(1024, 4) void gemm_w16(
    const bf16* __restrict__ A, int lda,
    const bf16* __restrict__ BT, int ldb,
    TC* __restrict__ C, int ldc, int gx) {
  __shared__ __align__(16) bf16 As[4 * 8192];
  __shared__ __align__(16) bf16 Bs[4 * 8192];
  const int tid  = threadIdx.x;
  const int lane = tid & 63;
  const int w    = tid >> 6;
  const int wm   = w >> 2;
  const int wn   = w & 3;
  const int lr   = lane & 15, lg = lane >> 4;
  const int fo   = 8 * (lg ^ ((lr >> 1) & 3));

  int nwg = gridDim.x;
  int bid = (int)blockIdx.x;
  int idx = (bid & 7) * (nwg >> 3) + (bid >> 3);
  int spos = idx % (8 * gx);
  const int m0 = ((idx / (8 * gx)) * 8 + (spos & 7)) * 256;
  const int n0 = (spos >> 3) * 256;

  const int srow = tid >> 2;
  const int ce   = 8 * ((tid & 3) ^ ((tid >> 3) & 3));
  const bf16* pA = A  + (size_t)(m0 + srow) * lda + ce;
  const bf16* pB = BT + (size_t)(n0 + srow) * ldb + ce;
  const int wofs = w * 512;
  const int aRd = (wm * 64 + lr) * 32 + fo;
  const int bRd = (wn * 64 + lr) * 32 + fo;

#define STAGE_A(kt) gload16(pA + ((kt) << 5), As + (((kt) & 3) << 13) + wofs)
#define STAGE_B(kt) gload16(pB + ((kt) << 5), Bs + (((kt) & 3) << 13) + wofs)

  f32x4 acc[4][4];
#pragma unroll
  for (int m = 0; m < 4; ++m)
#pragma unroll
    for (int n = 0; n < 4; ++n) acc[m][n] = (f32x4){0.f, 0.f, 0.f, 0.f};

#define KBODY(T, DOSTAGE, VMC) do {                                          \
    const bf16* Ab = As + (((T) & 3) << 13);                                 \
    const bf16* Bb = Bs + (((T) & 3) << 13);                                 \
    if (DOSTAGE) { STAGE_A((T) + 3); STAGE_B((T) + 3); }                     \
    bf16x8 bfv[4], af[4];                                                    \
    _Pragma("unroll")                                                        \
    for (int n = 0; n < 4; ++n) bfv[n] = *(const bf16x8*)&Bb[bRd + n * 512]; \
    _Pragma("unroll")                                                        \
    for (int m = 0; m < 4; ++m) af[m] = *(const bf16x8*)&Ab[aRd + m * 512];  \
    asm volatile("s_waitcnt lgkmcnt(0)" ::: "memory");                       \
    __builtin_amdgcn_sched_barrier(0);                                       \
    __builtin_amdgcn_s_setprio(1);                                           \
    _Pragma("unroll")                                                        \
    for (int m = 0; m < 4; ++m)                                              \
      _Pragma("unroll")                                                      \
      for (int n = 0; n < 4; ++n)                                            \
        acc[m][n] = __builtin_amdgcn_mfma_f32_16x16x32_bf16(af[m], bfv[n], acc[m][n], 0, 0, 0); \
    __builtin_amdgcn_s_setprio(0);                                           \
    asm volatile("s_waitcnt vmcnt(" #VMC ")" ::: "memory");                  \
    __builtin_amdgcn_s_barrier();                                            \
    __builtin_amdgcn_sched_barrier(0);                                       \
  } while (0)

  STAGE_A(0); STAGE_B(0); STAGE_A(1); STAGE_B(1); STAGE_A(2); STAGE_B(2);
  asm volatile("s_waitcnt vmcnt(4)" ::: "memory");
  __builtin_amdgcn_s_barrier();
  __builtin_amdgcn_sched_barrier(0);

#pragma unroll 4
  for (int t = 0; t < KT - 3; ++t) KBODY(t, true, 4);
  KBODY(KT - 3, false, 2);
  KBODY(KT - 2, false, 0);
  KBODY(KT - 1, false, 0);
#undef KBODY
#undef STAGE_A
#undef STAGE_B

  if constexpr (__is_same(TC, bf16)) {
    bf16* Ws = (w < 8 ? As : Bs) + (w & 7) * 4096;
#pragma unroll
    for (int m = 0; m < 4; ++m)
#pragma unroll
      for (int n = 0; n < 4; ++n)
#pragma unroll
        for (int reg = 0; reg < 4; ++reg) {
          int row = m * 16 + lg * 4 + reg;
          int slot = (n * 2 + (lr >> 3)) ^ (row & 7);
          Ws[row * 64 + slot * 8 + (lr & 7)] = __float2bfloat16(acc[m][n][reg]);
        }
    asm volatile("s_waitcnt lgkmcnt(0)" ::: "memory");
#pragma unroll
    for (int i = 0; i < 8; ++i) {
      int row = i * 8 + (lane >> 3);
      bf16x8 v = *(const bf16x8*)&Ws[row * 64 + ((lane & 7) ^ (lane >> 3)) * 8];
      int gcol = n0 + wn * 64 + (lane & 7) * 8;
      *(bf16x8*)&((bf16*)C)[(size_t)(m0 + wm * 64 + row) * ldc + gcol] = v;
    }
  } else {
#pragma unroll
    for (int m = 0; m < 4; ++m)
#pragma unroll
      for (int n = 0; n < 4; ++n) {
        int col = n0 + wn * 64 + n * 16 + lr;
        size_t rbase = (size_t)(m0 + wm * 64 + m * 16 + lg * 4);
#pragma unroll
        for (int reg = 0; reg < 4; ++reg)
          from_f(C[(rbase + reg) * ldc + col], acc[m][n][reg]);
      }
  }
}

// ---------------- round-4 128x128 MFMA GEMM — for the narrow BCdt slice ------
template <typename TC, bool MASK>
__global__ __launch_bounds__(256) void gemm_mfma(
    const bf16* __restrict__ A, int lda,
    const bf16* __restrict__ BT, int ldb,
    TC* __restrict__ C, int ldc, int Kdim, int Nvalid) {
  __shared__ __align__(16) bf16 As[128 * 32];
  __shared__ __align__(16) bf16 Bs[128 * 32];
  const int tid  = threadIdx.x;
  const int lane = tid & 63;
  const int w    = tid >> 6;
  const int m0 = blockIdx.y * 128;
  const int n0 = blockIdx.x * 128;

  const int rs0 = w * 32 + (lane >> 2);
  const int ce  = 8 * ((lane & 3) ^ ((lane >> 2) & 3));
  const int fo  = 8 * ((lane >> 4) ^ (lane & 3));
  const int lr  = lane & 15, lg = lane >> 4;
  const int wr = w >> 1, wc = w & 1;

  f32x4 acc[4][4];
#pragma unroll
  for (int m = 0; m < 4; ++m)
#pragma unroll
    for (int n = 0; n < 4; ++n) acc[m][n] = (f32x4){0.f, 0.f, 0.f, 0.f};

  const size_t arow0 = (size_t)(m0 + rs0) * lda;
  const size_t arow1 = (size_t)(m0 + rs0 + 16) * lda;
  const size_t brow0 = (size_t)(n0 + rs0) * ldb;
  const size_t brow1 = (size_t)(n0 + rs0 + 16) * ldb;
  bf16* lA0 = &As[(w * 2 + 0) * 512];
  bf16* lA1 = &As[(w * 2 + 1) * 512];
  bf16* lB0 = &Bs[(w * 2 + 0) * 512];
  bf16* lB1 = &Bs[(w * 2 + 1) * 512];

  for (int k0 = 0; k0 < Kdim; k0 += 32) {
    __syncthreads();
    gload16(A + arow0 + k0 + ce, lA0);
    gload16(A + arow1 + k0 + ce, lA1);
    gload16(BT + brow0 + k0 + ce, lB0);
    gload16(BT + brow1 + k0 + ce, lB1);
    __syncthreads();
    bf16x8 af[4], bfr[4];
#pragma unroll
    for (int m = 0; m < 4; ++m)
      af[m] = *(const bf16x8*)&As[(wr * 64 + m * 16 + lr) * 32 + fo];
#pragma unroll
    for (int n = 0; n < 4; ++n)
      bfr[n] = *(const bf16x8*)&Bs[(wc * 64 + n * 16 + lr) * 32 + fo];
#pragma unroll
    for (int m = 0; m < 4; ++m)
#pragma unroll
      for (int n = 0; n < 4; ++n)
        acc[m][n] = __builtin_amdgcn_mfma_f32_16x16x32_bf16(af[m], bfr[n], acc[m][n], 0, 0, 0);
  }

#pragma unroll
  for (int m = 0; m < 4; ++m)
#pragma unroll
    for (int n = 0; n < 4; ++n) {
      int col = n0 + wc * 64 + n * 16 + lr;
      if (MASK && col >= Nvalid) continue;
      size_t rbase = (size_t)(m0 + wr * 64 + m * 16 + lg * 4);
#pragma unroll
      for (int reg = 0; reg < 4; ++reg)
        from_f(C[(rbase + reg) * ldc + col], acc[m][n][reg]);
    }
}

// ---------------- cast fp32 -> bf16 (4/thread) ----------------
__global__ __launch_bounds__(256) void cast_bf16_kernel(
    const float* __restrict__ x, bf16* __restrict__ y) {
  size_t i = ((size_t)blockIdx.x * 256 + threadIdx.x) * 4;
  float4 v = *(const float4*)(x + i);
  y[i + 0] = __float2bfloat16(v.x);
  y[i + 1] = __float2bfloat16(v.y);
  y[i + 2] = __float2bfloat16(v.z);
  y[i + 3] = __float2bfloat16(v.w);
}

// ---------------- transpose + cast: WT[Npad][K] = W[K][N]^T ----------------
__global__ __launch_bounds__(256) void transpose_cast_kernel(
    const float* __restrict__ W, bf16* __restrict__ WT, int N, int K) {
  __shared__ float t[32][33];
  int n0 = blockIdx.x * 32, k0 = blockIdx.y * 32;
  int tx = threadIdx.x & 31, ty = threadIdx.x >> 5;
#pragma unroll
  for (int i = 0; i < 4; ++i) {
    int n = n0 + tx;
    t[ty + i * 8][tx] = (n < N) ? W[(size_t)(k0 + ty + i * 8) * N + n] : 0.f;
  }
  __syncthreads();
#pragma unroll
  for (int i = 0; i < 4; ++i) {
    int nn = ty + i * 8;
    WT[(size_t)(n0 + nn) * K + k0 + tx] = __float2bfloat16(t[tx][nn]);
  }
}

// ---------------- depthwise causal conv1d (K=4) + SiLU, 4 tokens/thread ------
__global__ __launch_bounds__(256) void conv_silu_kernel(
    const bf16* __restrict__ zx, const float* __restrict__ cw,
    const float* __restrict__ cb, bf16* __restrict__ xc) {
  int idx = blockIdx.x * 256 + threadIdx.x;
  int d8 = (idx & 511) * 8;
  int g = idx >> 9;
  int m0 = g * 4;
  int l0 = m0 & (SEQLEN - 1);
  int b = m0 >> 12;
  bf16x8 rows[7];
  bf16x8 zvec;
#pragma unroll
  for (int j = 0; j < 8; ++j) zvec[j] = 0;
#pragma unroll
  for (int r = 0; r < 7; ++r) {
    int li = l0 - 3 + r;
    rows[r] = (li >= 0)
        ? *(const bf16x8*)&zx[(size_t)(b * SEQLEN + li) * DPROJ + DINNER + d8]
        : zvec;
  }
  float cwv[4][8], cbv[8];
#pragma unroll
  for (int k = 0; k < 4; ++k) {
    float4 a = *(const float4*)(cw + k * DINNER + d8);
    float4 bb = *(const float4*)(cw + k * DINNER + d8 + 4);
    cwv[k][0] = a.x; cwv[k][1] = a.y; cwv[k][2] = a.z; cwv[k][3] = a.w;
    cwv[k][4] = bb.x; cwv[k][5] = bb.y; cwv[k][6] = bb.z; cwv[k][7] = bb.w;
  }
  {
    float4 a = *(const float4*)(cb + d8);
    float4 bb = *(const float4*)(cb + d8 + 4);
    cbv[0] = a.x; cbv[1] = a.y; cbv[2] = a.z; cbv[3] = a.w;
    cbv[4] = bb.x; cbv[5] = bb.y; cbv[6] = bb.z; cbv[7] = bb.w;
  }
#pragma unroll
  for (int j = 0; j < 4; ++j) {
    float acc[8];
#pragma unroll
    for (int e = 0; e < 8; ++e) acc[e] = cbv[e];
#pragma unroll
    for (int k = 0; k < 4; ++k)
#pragma unroll
      for (int e = 0; e < 8; ++e) acc[e] += bf2f(rows[j + k][e]) * cwv[k][e];
    bf16x8 o;
#pragma unroll
    for (int e = 0; e < 8; ++e) { bf16 h = __float2bfloat16(siluf(acc[e])); o[e] = *(short*)&h; }
    *(bf16x8*)&xc[(size_t)(m0 + j) * DINNER + d8] = o;
  }
}

// ---------------- fused B/C elu+1 + log-decay + per-chunk cumsum --------------
__global__ __launch_bounds__(256) void prep_cumsum_kernel(
    const bf16* __restrict__ zx, const float* __restrict__ A_log,
    const float* __restrict__ dt_bias, bf16* __restrict__ Bmb,
    bf16* __restrict__ Cmb, float* __restrict__ cs) {
  int bid = blockIdx.x;            // b*64 + c
  int c = bid & 63, b = bid >> 6;
  int m0 = b * SEQLEN + c * CHUNK;
  int tid = threadIdx.x;
  int s = tid >> 2, grp = (tid & 3) * 16;
  __shared__ float laT[64 * 65];
  __shared__ float segs[4][64];
  const bf16* row = zx + (size_t)(m0 + s) * DPROJ + 2 * DINNER;
  {
    union { bf16x8 v[2]; bf16 hh[16]; } u, o;
    u.v[0] = *(const bf16x8*)&row[grp];
    u.v[1] = *(const bf16x8*)&row[grp + 8];
#pragma unroll
    for (int i = 0; i < 16; ++i) {
      float bv = to_f(u.hh[i]);
      from_f(o.hh[i], bv > 0.f ? bv + 1.f : expf(bv));
    }
    *(bf16x8*)&Bmb[(size_t)(m0 + s) * 64 + grp] = o.v[0];
    *(bf16x8*)&Bmb[(size_t)(m0 + s) * 64 + grp + 8] = o.v[1];
    u.v[0] = *(const bf16x8*)&row[64 + grp];
    u.v[1] = *(const bf16x8*)&row[64 + grp + 8];
#pragma unroll
    for (int i = 0; i < 16; ++i) {
      float cv = to_f(u.hh[i]);
      from_f(o.hh[i], cv > 0.f ? cv + 1.f : expf(cv));
    }
    *(bf16x8*)&Cmb[(size_t)(m0 + s) * 64 + grp] = o.v[0];
    *(bf16x8*)&Cmb[(size_t)(m0 + s) * 64 + grp + 8] = o.v[1];
    u.v[0] = *(const bf16x8*)&row[128 + grp];
    u.v[1] = *(const bf16x8*)&row[128 + grp + 8];
#pragma unroll
    for (int i = 0; i < 16; ++i) {
      int j = grp + i;
      float dtl = to_f(u.hh[i]) + dt_bias[j];
      float dt = dtl > 20.f ? dtl : log1pf(expf(dtl));
      laT[j * 65 + s] = -dt * expf(A_log[j]);
    }
  }
  __syncthreads();
  int j = tid & 63, sg = tid >> 6;
  float p = 0.f;
#pragma unroll
  for (int i = 0; i < 16; ++i) p += laT[j * 65 + sg * 16 + i];
  segs[sg][j] = p;
  __syncthreads();
  float off = (sg > 0 ? segs[0][j] : 0.f) + (sg > 1 ? segs[1][j] : 0.f) +
              (sg > 2 ? segs[2][j] : 0.f);
  float acc = off;
#pragma unroll
  for (int i = 0; i < 16; ++i) {
    acc += laT[j * 65 + sg * 16 + i];
    cs[(size_t)(m0 + sg * 16 + i) * 64 + j] = acc;
  }
}

// ---------------- per-chunk state via MFMA: stT[p][n] = sum_s v[s][p]*ksc[s][n] ----------------
__global__ __launch_bounds__(256) void states_mfma(
    const bf16* __restrict__ Bmb, const bf16* __restrict__ xc,
    const float* __restrict__ cs, bf16* __restrict__ st) {
  int bid = blockIdx.x;
  int c = bid & 63, h = (bid >> 6) & 63, b = bid >> 12;
  int m0 = b * SEQLEN + c * CHUNK;
  int tid = threadIdx.x, lane = tid & 63, w = tid >> 6;
  int lr = lane & 15, lg = lane >> 4;
  __shared__ bf16 vT[64 * 72];
  __shared__ bf16 kT[64 * 72];
  int s4 = tid >> 2, c16 = (tid & 3) * 16;
  float cstot = cs[(size_t)(m0 + 63) * 64 + h];
  float ws = expf(cstot - cs[(size_t)(m0 + s4) * 64 + h]);
  {
    union { bf16x8 v[2]; bf16 hh[16]; } u;
    const bf16x8* pv = (const bf16x8*)&xc[(size_t)(m0 + s4) * DINNER + h * 64 + c16];
    u.v[0] = pv[0]; u.v[1] = pv[1];
#pragma unroll
    for (int i = 0; i < 16; ++i) vT[(c16 + i) * 72 + s4] = u.hh[i];
    const bf16x8* pk = (const bf16x8*)&Bmb[(size_t)(m0 + s4) * 64 + c16];
    u.v[0] = pk[0]; u.v[1] = pk[1];
#pragma unroll
    for (int i = 0; i < 16; ++i) kT[(c16 + i) * 72 + s4] = __float2bfloat16(to_f(u.hh[i]) * ws);
  }
  __syncthreads();
  f32x4 acc[4];
#pragma unroll
  for (int ct = 0; ct < 4; ++ct) acc[ct] = (f32x4){0.f, 0.f, 0.f, 0.f};
#pragma unroll
  for (int ks = 0; ks < 2; ++ks) {
    bf16x8 af = *(const bf16x8*)&vT[(w * 16 + lr) * 72 + ks * 32 + lg * 8];
#pragma unroll
    for (int ct = 0; ct < 4; ++ct) {
      bf16x8 bf_ = *(const bf16x8*)&kT[(ct * 16 + lr) * 72 + ks * 32 + lg * 8];
      acc[ct] = __builtin_amdgcn_mfma_f32_16x16x32_bf16(af, bf_, acc[ct], 0, 0, 0);
    }
  }
  size_t ob = (((size_t)(b * NHEADS + h)) * NCHUNK + c) * 4096;
#pragma unroll
  for (int ct = 0; ct < 4; ++ct) {
    int n = ct * 16 + lr;
#pragma unroll
    for (int r = 0; r < 4; ++r) {
      int p = w * 16 + lg * 4 + r;
      from_f(st[ob + (size_t)p * 64 + n], acc[ct][r]);
    }
  }
}

// ---------------- sequential scan over chunks; dec[] staged, ring-4 prefetch --
__global__ __launch_bounds__(256) void scan_kernel(
    const float* __restrict__ cs, bf16* __restrict__ st) {
  int bid = blockIdx.x;
  int bh = bid >> 2, qq = bid & 3;
  int b = bh >> 6, h = bh & 63;
  int tid = threadIdx.x;
  __shared__ float dec[64];
  if (tid < 64)
    dec[tid] = expf(cs[(size_t)(b * SEQLEN + tid * CHUNK + 63) * 64 + h]);
  int e0 = qq * 1024 + tid * 4;
  float hr[4] = {0.f, 0.f, 0.f, 0.f};
  size_t base = (size_t)bh * NCHUNK * 4096;
  typedef __attribute__((ext_vector_type(4))) short bf16x4;
  union U { bf16x4 v; bf16 hh[4]; };
  U buf[4];
  buf[0].v = *(bf16x4*)(st + base + 0 * 4096 + e0);
  buf[1].v = *(bf16x4*)(st + base + 1 * 4096 + e0);
  buf[2].v = *(bf16x4*)(st + base + 2 * 4096 + e0);
  __syncthreads();
#pragma unroll 4
  for (int c = 0; c < NCHUNK; ++c) {
    if (c + 3 < NCHUNK)
      buf[(c + 3) & 3].v = *(bf16x4*)(st + base + (size_t)(c + 3) * 4096 + e0);
    float d = dec[c];
    U out;
#pragma unroll
    for (int i = 0; i < 4; ++i) {
      float sv = to_f(buf[c & 3].hh[i]);
      from_f(out.hh[i], hr[i]);
      hr[i] = d * hr[i] + sv;
    }
    *(bf16x4*)(st + base + (size_t)c * 4096 + e0) = out.v;
  }
}

// ---------------- per-chunk output via MFMA ----------------
__global__ __launch_bounds__(256) void chunk_out_mfma(
    const bf16* __restrict__ Bmb, const bf16* __restrict__ Cmb,
    const bf16* __restrict__ xc, const float* __restrict__ cs,
    const bf16* __restrict__ st, const float* __restrict__ Dp,
    bf16* __restrict__ zx) {
  int bid = blockIdx.x;
  int c = bid & 63, h = (bid >> 6) & 63, b = bid >> 12;
  int m0 = b * SEQLEN + c * CHUNK;
  int tid = threadIdx.x, lane = tid & 63, w = tid >> 6;
  int lr = lane & 15, lg = lane >> 4;
  __shared__ bf16 qL[64 * 72];
  __shared__ bf16 kL[64 * 72];
  __shared__ bf16 A2[64 * 136];
  __shared__ bf16 B2[64 * 136];
  __shared__ float csl[64];
  int s4 = tid >> 2, c16 = (tid & 3) * 16;

  if (tid < 64) csl[tid] = cs[(size_t)(m0 + tid) * 64 + h];
  {
    const bf16x8* pq = (const bf16x8*)&Cmb[(size_t)(m0 + s4) * 64 + c16];
    *(bf16x8*)&qL[s4 * 72 + c16] = pq[0];
    *(bf16x8*)&qL[s4 * 72 + c16 + 8] = pq[1];
    const bf16x8* pk = (const bf16x8*)&Bmb[(size_t)(m0 + s4) * 64 + c16];
    *(bf16x8*)&kL[s4 * 72 + c16] = pk[0];
    *(bf16x8*)&kL[s4 * 72 + c16 + 8] = pk[1];
  }
  {
    union { bf16x8 v[2]; bf16 hh[16]; } u;
    const bf16x8* pv = (const bf16x8*)&xc[(size_t)(m0 + s4) * DINNER + h * 64 + c16];
    u.v[0] = pv[0]; u.v[1] = pv[1];
#pragma unroll
    for (int i = 0; i < 16; ++i) B2[(c16 + i) * 136 + s4] = u.hh[i];
  }
  {
    size_t hb = (((size_t)(b * NHEADS + h)) * NCHUNK + c) * 4096;
    const bf16x8* ph = (const bf16x8*)&st[hb + (size_t)s4 * 64 + c16];
    *(bf16x8*)&B2[s4 * 136 + 64 + c16] = ph[0];
    *(bf16x8*)&B2[s4 * 136 + 64 + c16 + 8] = ph[1];
  }
  __syncthreads();

  f32x4 acc1[4];
#pragma unroll
  for (int ct = 0; ct < 4; ++ct) acc1[ct] = (f32x4){0.f, 0.f, 0.f, 0.f};
#pragma unroll
  for (int ks = 0; ks < 2; ++ks) {
    bf16x8 af = *(const bf16x8*)&qL[(w * 16 + lr) * 72 + ks * 32 + lg * 8];
#pragma unroll
    for (int ct = 0; ct < 4; ++ct) {
      bf16x8 bf_ = *(const bf16x8*)&kL[(ct * 16 + lr) * 72 + ks * 32 + lg * 8];
      acc1[ct] = __builtin_amdgcn_mfma_f32_16x16x32_bf16(af, bf_, acc1[ct], 0, 0, 0);
    }
  }
  {
    float es = expf(csl[s4]);
    union { bf16x8 v[2]; bf16 hh[16]; } u;
    const bf16x8* pq = (const bf16x8*)&qL[s4 * 72 + c16];
    u.v[0] = pq[0]; u.v[1] = pq[1];
#pragma unroll
    for (int i = 0; i < 16; ++i) u.hh[i] = __float2bfloat16(to_f(u.hh[i]) * es);
    *(bf16x8*)&A2[s4 * 136 + 64 + c16] = u.v[0];
    *(bf16x8*)&A2[s4 * 136 + 64 + c16 + 8] = u.v[1];
  }
#pragma unroll
  for (int ct = 0; ct < 4; ++ct) {
    int t = ct * 16 + lr;
#pragma unroll
    for (int r = 0; r < 4; ++r) {
      int s = w * 16 + lg * 4 + r;
      float val = (t <= s) ? acc1[ct][r] * expf(csl[s] - csl[t]) : 0.f;
      A2[s * 136 + t] = __float2bfloat16(val);
    }
  }
  __syncthreads();

  float Dh = Dp[h];
  f32x4 acc2[4];
#pragma unroll
  for (int ct = 0; ct < 4; ++ct) {
    int p = ct * 16 + lr;
#pragma unroll
    for (int r = 0; r < 4; ++r)
      acc2[ct][r] = Dh * to_f(B2[p * 136 + (w * 16 + lg * 4 + r)]);
  }
#pragma unroll
  for (int ks = 0; ks < 4; ++ks) {
    bf16x8 af = *(const bf16x8*)&A2[(w * 16 + lr) * 136 + ks * 32 + lg * 8];
#pragma unroll
    for (int ct = 0; ct < 4; ++ct) {
      bf16x8 bf_ = *(const bf16x8*)&B2[(ct * 16 + lr) * 136 + ks * 32 + lg * 8];
      acc2[ct] = __builtin_amdgcn_mfma_f32_16x16x32_bf16(af, bf_, acc2[ct], 0, 0, 0);
    }
  }
  __syncthreads();
#pragma unroll
  for (int ct = 0; ct < 4; ++ct) {
    int p = ct * 16 + lr;
#pragma unroll
    for (int r = 0; r < 4; ++r)
      qL[(w * 16 + lg * 4 + r) * 72 + p] = __float2bfloat16(acc2[ct][r]);
  }
  __syncthreads();
  {
    const bf16x8* py = (const bf16x8*)&qL[s4 * 72 + c16];
    bf16x8* pg = (bf16x8*)&zx[(size_t)(m0 + s4) * DPROJ + DINNER + h * 64 + c16];
    pg[0] = py[0]; pg[1] = py[1];
  }
}

// ---------------- RMSNorm over 4096 + silu(z) gate, bf16x8 ----------------
__global__ __launch_bounds__(256) void rmsnorm_gate_kernel(
    bf16* __restrict__ zx, const float* __restrict__ scale) {
  int m = blockIdx.x;
  int tid = threadIdx.x;
  bf16* row = zx + (size_t)m * DPROJ;
  float vals[16];
  float ss = 0.f;
#pragma unroll
  for (int g = 0; g < 2; ++g) {
    int d8 = (tid + g * 256) * 8;
    bf16x8 yv = *(const bf16x8*)&row[DINNER + d8];
#pragma unroll
    for (int j = 0; j < 8; ++j) {
      float y = bf2f(yv[j]);
      vals[g * 8 + j] = y;
      ss += y * y;
    }
  }
#pragma unroll
  for (int off = 32; off > 0; off >>= 1) ss += __shfl_down(ss, off, 64);
  __shared__ float red[4];
  if ((tid & 63) == 0) red[tid >> 6] = ss;
  __syncthreads();
  float tot = red[0] + red[1] + red[2] + red[3];
  float inv = rsqrtf(tot / (float)DINNER + RMS_EPS);
#pragma unroll
  for (int g = 0; g < 2; ++g) {
    int d8 = (tid + g * 256) * 8;
    bf16x8 zv = *(const bf16x8*)&row[d8];
    const float* sc = scale + d8;
    bf16x8 o;
#pragma unroll
    for (int j = 0; j < 8; ++j) {
      bf16 hh = __float2bfloat16(vals[g * 8 + j] * inv * sc[j] * siluf(bf2f(zv[j])));
      o[j] = *(short*)&hh;
    }
    *(bf16x8*)&row[DINNER + d8] = o;
  }
}

// ---------------- launch ----------------
extern "C" void kernel_launch(void* const* d_in, const int* in_sizes, int n_in,
                              void* d_out, int out_size, void* d_ws, size_t ws_size,
                              hipStream_t stream) {
  const float* u       = (const float*)d_in[0];
  const float* Win     = (const float*)d_in[1];
  const float* cw      = (const float*)d_in[2];
  const float* cb      = (const float*)d_in[3];
  const float* A_log   = (const float*)d_in[4];
  const float* dt_bias = (const float*)d_in[5];
  const float* Dp      = (const float*)d_in[6];
  const float* nscale  = (const float*)d_in[7];
  const float* Wout    = (const float*)d_in[8];
  float* out = (float*)d_out;

  bf16* zx = (bf16*)d_ws;
  bf16* xc = zx + (size_t)MTOK * DPROJ;
  bf16* ub = xc;                                  // overlay: ub dead before xc written
  bf16* wT = xc + (size_t)MTOK * DINNER;
  bf16* Bmb = wT + (size_t)DPROJ_PAD * DMODEL;
  bf16* Cmb = Bmb + (size_t)MTOK * 64;
  float* cs = (float*)(Cmb + (size_t)MTOK * 64);
  bf16* st = (bf16*)d_out;                        // chunk states, 64 MiB

  cast_bf16_kernel<<<(MTOK * DMODEL) / (256 * 4), 256, 0, stream>>>(u, ub);
  transpose_cast_kernel<<<dim3(DPROJ_PAD / 32, DMODEL / 32), 256, 0, stream>>>(Win, wT, DPROJ, DMODEL);
  // 1a) in-projection z|x columns: N=8192, 16-wave kernel, grid 1024
  gemm_w16<bf16, DMODEL / 32><<<(2 * DINNER / 256) * (MTOK / 256), 1024, 0, stream>>>(
      ub, DMODEL, wT, DMODEL, zx, DPROJ, 2 * DINNER / 256);
  // 1b) in-projection BCdt columns: N=192 (pad 256), 128x128 kernel
  gemm_mfma<bf16, true><<<dim3(2, MTOK / 128), 256, 0, stream>>>(
      ub, DMODEL, wT + (size_t)(2 * DINNER) * DMODEL, DMODEL,
      zx + 2 * DINNER, DPROJ, DMODEL, 192);
  transpose_cast_kernel<<<dim3(DMODEL / 32, DINNER / 32), 256, 0, stream>>>(Wout, wT, DMODEL, DINNER);
  conv_silu_kernel<<<(MTOK / 4) * 512 / 256, 256, 0, stream>>>(zx, cw, cb, xc);
  prep_cumsum_kernel<<<BATCH * NCHUNK, 256, 0, stream>>>(zx, A_log, dt_bias, Bmb, Cmb, cs);
  states_mfma<<<BATCH * NHEADS * NCHUNK, 256, 0, stream>>>(Bmb, xc, cs, st);
  scan_kernel<<<BATCH * NHEADS * 4, 256, 0, stream>>>(cs, st);
  chunk_out_mfma<<<BATCH * NHEADS * NCHUNK, 256, 0, stream>>>(Bmb, Cmb, xc, cs, st, Dp, zx);
  rmsnorm_gate_kernel<<<MTOK, 256, 0, stream>>>(zx, nscale);
  // 9) out-projection: 16-wave kernel, float out, grid 256, KT=128
  gemm_w16<float, DINNER / 32><<<(DMODEL / 256) * (MTOK / 256), 1024, 0, stream>>>(
      zx + DINNER, DPROJ, wT, DINNER, out, DMODEL, DMODEL / 256);
}

// Round 16
// 635.369 us; speedup vs baseline: 1.1620x; 1.0127x over previous
//
#include <hip/hip_runtime.h>
#include <hip/hip_bf16.h>
#include <cstdint>
#include <cstddef>

// ---------------- problem constants ----------------
#define BATCH   2
#define SEQLEN  4096
#define DMODEL  2048
#define DINNER  4096
#define NHEADS  64
#define HEADDIM 64
#define DSTATE  64
#define CHUNK   64
#define NCHUNK  (SEQLEN/CHUNK)      // 64
#define DPROJ   8384
#define DPROJ_PAD 8448
#define MTOK    (BATCH*SEQLEN)      // 8192
#define RMS_EPS 1e-6f

typedef __hip_bfloat16 bf16;
typedef __attribute__((ext_vector_type(8))) short bf16x8;
typedef __attribute__((ext_vector_type(4))) float f32x4;

__device__ __forceinline__ float siluf(float x) { return x / (1.f + expf(-x)); }
__device__ __forceinline__ float to_f(float x) { return x; }
__device__ __forceinline__ float to_f(bf16 x) { return __bfloat162float(x); }
__device__ __forceinline__ float bf2f(short s) { bf16 h; *(short*)&h = s; return __bfloat162float(h); }
__device__ __forceinline__ void from_f(float& d, float x) { d = x; }
__device__ __forceinline__ void from_f(bf16& d, float x) { d = __float2bfloat16(x); }

__device__ __forceinline__ void gload16(const void* g, void* l) {
  __builtin_amdgcn_global_load_lds(
      (const __attribute__((address_space(1))) void*)g,
      (__attribute__((address_space(3))) void*)l, 16, 0, 0);
}

// ---------------- gemm_w16p2: 256x256 tile, 16 waves, period-2 K-loop --------
// C[M,N] = A[M,K] @ BT[N,K]^T.  1024 thr = 16 waves (4M x 4N), 64x64/wave
// (acc 64 AGPR -> 4 waves/SIMD).  BK=32, ring-4 LDS (128 KB).
// ONE barrier per 2 K-tiles: period p = { stage(2p+2,2p+3) -> reads(2p)+MFMA
// -> reads(2p+1)+MFMA -> vmcnt(0) -> barrier }.
// Race audit: stage targets bufs whose reads finished before the previous
// barrier; each wave's vmcnt(0) precedes the shared barrier, so all waves'
// gloads for tiles 2p+2,2p+3 are visible when period p+1 reads them.
// 4-slot XOR swizzle both sides (T2), strip-grouped XCD swizzle (T1),
// setprio around MFMA (T5).
template <typename TC, int KT>
__global__ __launch_bounds__(1024, 4) void gemm_w16p2(
    const bf16* __restrict__ A, int lda,
    const bf16* __restrict__ BT, int ldb,
    TC* __restrict__ C, int ldc, int gx) {
  __shared__ __align__(16) bf16 As[4 * 8192];
  __shared__ __align__(16) bf16 Bs[4 * 8192];
  const int tid  = threadIdx.x;
  const int lane = tid & 63;
  const int w    = tid >> 6;
  const int wm   = w >> 2;
  const int wn   = w & 3;
  const int lr   = lane & 15, lg = lane >> 4;
  const int fo   = 8 * (lg ^ ((lr >> 1) & 3));

  // strip-grouped bijective XCD swizzle (nwg%8==0, Mtiles%8==0)
  int nwg = gridDim.x;
  int bid = (int)blockIdx.x;
  int idx = (bid & 7) * (nwg >> 3) + (bid >> 3);
  int spos = idx % (8 * gx);
  const int m0 = ((idx / (8 * gx)) * 8 + (spos & 7)) * 256;
  const int n0 = (spos >> 3) * 256;

  const int srow = tid >> 2;
  const int ce   = 8 * ((tid & 3) ^ ((tid >> 3) & 3));
  const bf16* pA = A  + (size_t)(m0 + srow) * lda + ce;
  const bf16* pB = BT + (size_t)(n0 + srow) * ldb + ce;
  const int wofs = w * 512;
  const int aRd = (wm * 64 + lr) * 32 + fo;
  const int bRd = (wn * 64 + lr) * 32 + fo;

#define STAGE_A(kt) gload16(pA + ((kt) << 5), As + (((kt) & 3) << 13) + wofs)
#define STAGE_B(kt) gload16(pB + ((kt) << 5), Bs + (((kt) & 3) << 13) + wofs)

  f32x4 acc[4][4];
#pragma unroll
  for (int m = 0; m < 4; ++m)
#pragma unroll
    for (int n = 0; n < 4; ++n) acc[m][n] = (f32x4){0.f, 0.f, 0.f, 0.f};

  // one tile's read+MFMA (no sync; lgkm-gated)
#define TILE(T) do {                                                         \
    const bf16* Ab = As + (((T) & 3) << 13);                                 \
    const bf16* Bb = Bs + (((T) & 3) << 13);                                 \
    bf16x8 bfv[4], af[4];                                                    \
    _Pragma("unroll")                                                        \
    for (int n = 0; n < 4; ++n) bfv[n] = *(const bf16x8*)&Bb[bRd + n * 512]; \
    _Pragma("unroll")                                                        \
    for (int m = 0; m < 4; ++m) af[m] = *(const bf16x8*)&Ab[aRd + m * 512];  \
    asm volatile("s_waitcnt lgkmcnt(0)" ::: "memory");                       \
    __builtin_amdgcn_sched_barrier(0);                                       \
    __builtin_amdgcn_s_setprio(1);                                           \
    _Pragma("unroll")                                                        \
    for (int m = 0; m < 4; ++m)                                              \
      _Pragma("unroll")                                                      \
      for (int n = 0; n < 4; ++n)                                            \
        acc[m][n] = __builtin_amdgcn_mfma_f32_16x16x32_bf16(af[m], bfv[n], acc[m][n], 0, 0, 0); \
    __builtin_amdgcn_s_setprio(0);                                           \
  } while (0)

  // period: stage next pair early, compute current pair, drain, barrier
#define PERIOD(P, DOSTAGE) do {                                              \
    if (DOSTAGE) { STAGE_A(2 * (P) + 2); STAGE_B(2 * (P) + 2);               \
                   STAGE_A(2 * (P) + 3); STAGE_B(2 * (P) + 3); }             \
    TILE(2 * (P));                                                           \
    TILE(2 * (P) + 1);                                                       \
    asm volatile("s_waitcnt vmcnt(0)" ::: "memory");                         \
    __builtin_amdgcn_s_barrier();                                            \
    __builtin_amdgcn_sched_barrier(0);                                       \
  } while (0)

  // prologue: stage tiles 0,1; drain; barrier
  STAGE_A(0); STAGE_B(0); STAGE_A(1); STAGE_B(1);
  asm volatile("s_waitcnt vmcnt(0)" ::: "memory");
  __builtin_amdgcn_s_barrier();
  __builtin_amdgcn_sched_barrier(0);

  const int NP = KT / 2;
#pragma unroll 2
  for (int p = 0; p < NP - 1; ++p) PERIOD(p, true);
  PERIOD(NP - 1, false);
#undef PERIOD
#undef TILE
#undef STAGE_A
#undef STAGE_B

  if constexpr (__is_same(TC, bf16)) {
    // vectorized epilogue: 16 waves x 4096-elem private regions; 8-slot XOR
    // swizzle, key = row&7 on BOTH sides (rule #21).
    bf16* Ws = (w < 8 ? As : Bs) + (w & 7) * 4096;
#pragma unroll
    for (int m = 0; m < 4; ++m)
#pragma unroll
      for (int n = 0; n < 4; ++n)
#pragma unroll
        for (int reg = 0; reg < 4; ++reg) {
          int row = m * 16 + lg * 4 + reg;
          int slot = (n * 2 + (lr >> 3)) ^ (row & 7);
          Ws[row * 64 + slot * 8 + (lr & 7)] = __float2bfloat16(acc[m][n][reg]);
        }
    asm volatile("s_waitcnt lgkmcnt(0)" ::: "memory");
#pragma unroll
    for (int i = 0; i < 8; ++i) {
      int row = i * 8 + (lane >> 3);
      bf16x8 v = *(const bf16x8*)&Ws[row * 64 + ((lane & 7) ^ (lane >> 3)) * 8];
      int gcol = n0 + wn * 64 + (lane & 7) * 8;
      *(bf16x8*)&((bf16*)C)[(size_t)(m0 + wm * 64 + row) * ldc + gcol] = v;
    }
  } else {
    // float path: scalar stores (C/D layout col=lane&15, row=(lane>>4)*4+reg)
#pragma unroll
    for (int m = 0; m < 4; ++m)
#pragma unroll
      for (int n = 0; n < 4; ++n) {
        int col = n0 + wn * 64 + n * 16 + lr;
        size_t rbase = (size_t)(m0 + wm * 64 + m * 16 + lg * 4);
#pragma unroll
        for (int reg = 0; reg < 4; ++reg)
          from_f(C[(rbase + reg) * ldc + col], acc[m][n][reg]);
      }
  }
}

// ---------------- round-4 128x128 MFMA GEMM — for the narrow BCdt slice ------
template <typename TC, bool MASK>
__global__ __launch_bounds__(256) void gemm_mfma(
    const bf16* __restrict__ A, int lda,
    const bf16* __restrict__ BT, int ldb,
    TC* __restrict__ C, int ldc, int Kdim, int Nvalid) {
  __shared__ __align__(16) bf16 As[128 * 32];
  __shared__ __align__(16) bf16 Bs[128 * 32];
  const int tid  = threadIdx.x;
  const int lane = tid & 63;
  const int w    = tid >> 6;
  const int m0 = blockIdx.y * 128;
  const int n0 = blockIdx.x * 128;

  const int rs0 = w * 32 + (lane >> 2);
  const int ce  = 8 * ((lane & 3) ^ ((lane >> 2) & 3));
  const int fo  = 8 * ((lane >> 4) ^ (lane & 3));
  const int lr  = lane & 15, lg = lane >> 4;
  const int wr = w >> 1, wc = w & 1;

  f32x4 acc[4][4];
#pragma unroll
  for (int m = 0; m < 4; ++m)
#pragma unroll
    for (int n = 0; n < 4; ++n) acc[m][n] = (f32x4){0.f, 0.f, 0.f, 0.f};

  const size_t arow0 = (size_t)(m0 + rs0) * lda;
  const size_t arow1 = (size_t)(m0 + rs0 + 16) * lda;
  const size_t brow0 = (size_t)(n0 + rs0) * ldb;
  const size_t brow1 = (size_t)(n0 + rs0 + 16) * ldb;
  bf16* lA0 = &As[(w * 2 + 0) * 512];
  bf16* lA1 = &As[(w * 2 + 1) * 512];
  bf16* lB0 = &Bs[(w * 2 + 0) * 512];
  bf16* lB1 = &Bs[(w * 2 + 1) * 512];

  for (int k0 = 0; k0 < Kdim; k0 += 32) {
    __syncthreads();
    gload16(A + arow0 + k0 + ce, lA0);
    gload16(A + arow1 + k0 + ce, lA1);
    gload16(BT + brow0 + k0 + ce, lB0);
    gload16(BT + brow1 + k0 + ce, lB1);
    __syncthreads();
    bf16x8 af[4], bfr[4];
#pragma unroll
    for (int m = 0; m < 4; ++m)
      af[m] = *(const bf16x8*)&As[(wr * 64 + m * 16 + lr) * 32 + fo];
#pragma unroll
    for (int n = 0; n < 4; ++n)
      bfr[n] = *(const bf16x8*)&Bs[(wc * 64 + n * 16 + lr) * 32 + fo];
#pragma unroll
    for (int m = 0; m < 4; ++m)
#pragma unroll
      for (int n = 0; n < 4; ++n)
        acc[m][n] = __builtin_amdgcn_mfma_f32_16x16x32_bf16(af[m], bfr[n], acc[m][n], 0, 0, 0);
  }

#pragma unroll
  for (int m = 0; m < 4; ++m)
#pragma unroll
    for (int n = 0; n < 4; ++n) {
      int col = n0 + wc * 64 + n * 16 + lr;
      if (MASK && col >= Nvalid) continue;
      size_t rbase = (size_t)(m0 + wr * 64 + m * 16 + lg * 4);
#pragma unroll
      for (int reg = 0; reg < 4; ++reg)
        from_f(C[(rbase + reg) * ldc + col], acc[m][n][reg]);
    }
}

// ---------------- cast fp32 -> bf16 (4/thread) ----------------
__global__ __launch_bounds__(256) void cast_bf16_kernel(
    const float* __restrict__ x, bf16* __restrict__ y) {
  size_t i = ((size_t)blockIdx.x * 256 + threadIdx.x) * 4;
  float4 v = *(const float4*)(x + i);
  y[i + 0] = __float2bfloat16(v.x);
  y[i + 1] = __float2bfloat16(v.y);
  y[i + 2] = __float2bfloat16(v.z);
  y[i + 3] = __float2bfloat16(v.w);
}

// ---------------- transpose + cast: WT[Npad][K] = W[K][N]^T ----------------
__global__ __launch_bounds__(256) void transpose_cast_kernel(
    const float* __restrict__ W, bf16* __restrict__ WT, int N, int K) {
  __shared__ float t[32][33];
  int n0 = blockIdx.x * 32, k0 = blockIdx.y * 32;
  int tx = threadIdx.x & 31, ty = threadIdx.x >> 5;
#pragma unroll
  for (int i = 0; i < 4; ++i) {
    int n = n0 + tx;
    t[ty + i * 8][tx] = (n < N) ? W[(size_t)(k0 + ty + i * 8) * N + n] : 0.f;
  }
  __syncthreads();
#pragma unroll
  for (int i = 0; i < 4; ++i) {
    int nn = ty + i * 8;
    WT[(size_t)(n0 + nn) * K + k0 + tx] = __float2bfloat16(t[tx][nn]);
  }
}

// ---------------- depthwise causal conv1d (K=4) + SiLU, 4 tokens/thread ------
__global__ __launch_bounds__(256) void conv_silu_kernel(
    const bf16* __restrict__ zx, const float* __restrict__ cw,
    const float* __restrict__ cb, bf16* __restrict__ xc) {
  int idx = blockIdx.x * 256 + threadIdx.x;
  int d8 = (idx & 511) * 8;
  int g = idx >> 9;
  int m0 = g * 4;
  int l0 = m0 & (SEQLEN - 1);
  int b = m0 >> 12;
  bf16x8 rows[7];
  bf16x8 zvec;
#pragma unroll
  for (int j = 0; j < 8; ++j) zvec[j] = 0;
#pragma unroll
  for (int r = 0; r < 7; ++r) {
    int li = l0 - 3 + r;
    rows[r] = (li >= 0)
        ? *(const bf16x8*)&zx[(size_t)(b * SEQLEN + li) * DPROJ + DINNER + d8]
        : zvec;
  }
  float cwv[4][8], cbv[8];
#pragma unroll
  for (int k = 0; k < 4; ++k) {
    float4 a = *(const float4*)(cw + k * DINNER + d8);
    float4 bb = *(const float4*)(cw + k * DINNER + d8 + 4);
    cwv[k][0] = a.x; cwv[k][1] = a.y; cwv[k][2] = a.z; cwv[k][3] = a.w;
    cwv[k][4] = bb.x; cwv[k][5] = bb.y; cwv[k][6] = bb.z; cwv[k][7] = bb.w;
  }
  {
    float4 a = *(const float4*)(cb + d8);
    float4 bb = *(const float4*)(cb + d8 + 4);
    cbv[0] = a.x; cbv[1] = a.y; cbv[2] = a.z; cbv[3] = a.w;
    cbv[4] = bb.x; cbv[5] = bb.y; cbv[6] = bb.z; cbv[7] = bb.w;
  }
#pragma unroll
  for (int j = 0; j < 4; ++j) {
    float acc[8];
#pragma unroll
    for (int e = 0; e < 8; ++e) acc[e] = cbv[e];
#pragma unroll
    for (int k = 0; k < 4; ++k)
#pragma unroll
      for (int e = 0; e < 8; ++e) acc[e] += bf2f(rows[j + k][e]) * cwv[k][e];
    bf16x8 o;
#pragma unroll
    for (int e = 0; e < 8; ++e) { bf16 h = __float2bfloat16(siluf(acc[e])); o[e] = *(short*)&h; }
    *(bf16x8*)&xc[(size_t)(m0 + j) * DINNER + d8] = o;
  }
}

// ---------------- fused B/C elu+1 + log-decay + per-chunk cumsum --------------
__global__ __launch_bounds__(256) void prep_cumsum_kernel(
    const bf16* __restrict__ zx, const float* __restrict__ A_log,
    const float* __restrict__ dt_bias, bf16* __restrict__ Bmb,
    bf16* __restrict__ Cmb, float* __restrict__ cs) {
  int bid = blockIdx.x;            // b*64 + c
  int c = bid & 63, b = bid >> 6;
  int m0 = b * SEQLEN + c * CHUNK;
  int tid = threadIdx.x;
  int s = tid >> 2, grp = (tid & 3) * 16;
  __shared__ float laT[64 * 65];
  __shared__ float segs[4][64];
  const bf16* row = zx + (size_t)(m0 + s) * DPROJ + 2 * DINNER;
  {
    union { bf16x8 v[2]; bf16 hh[16]; } u, o;
    u.v[0] = *(const bf16x8*)&row[grp];
    u.v[1] = *(const bf16x8*)&row[grp + 8];
#pragma unroll
    for (int i = 0; i < 16; ++i) {
      float bv = to_f(u.hh[i]);
      from_f(o.hh[i], bv > 0.f ? bv + 1.f : expf(bv));
    }
    *(bf16x8*)&Bmb[(size_t)(m0 + s) * 64 + grp] = o.v[0];
    *(bf16x8*)&Bmb[(size_t)(m0 + s) * 64 + grp + 8] = o.v[1];
    u.v[0] = *(const bf16x8*)&row[64 + grp];
    u.v[1] = *(const bf16x8*)&row[64 + grp + 8];
#pragma unroll
    for (int i = 0; i < 16; ++i) {
      float cv = to_f(u.hh[i]);
      from_f(o.hh[i], cv > 0.f ? cv + 1.f : expf(cv));
    }
    *(bf16x8*)&Cmb[(size_t)(m0 + s) * 64 + grp] = o.v[0];
    *(bf16x8*)&Cmb[(size_t)(m0 + s) * 64 + grp + 8] = o.v[1];
    u.v[0] = *(const bf16x8*)&row[128 + grp];
    u.v[1] = *(const bf16x8*)&row[128 + grp + 8];
#pragma unroll
    for (int i = 0; i < 16; ++i) {
      int j = grp + i;
      float dtl = to_f(u.hh[i]) + dt_bias[j];
      float dt = dtl > 20.f ? dtl : log1pf(expf(dtl));
      laT[j * 65 + s] = -dt * expf(A_log[j]);
    }
  }
  __syncthreads();
  int j = tid & 63, sg = tid >> 6;
  float p = 0.f;
#pragma unroll
  for (int i = 0; i < 16; ++i) p += laT[j * 65 + sg * 16 + i];
  segs[sg][j] = p;
  __syncthreads();
  float off = (sg > 0 ? segs[0][j] : 0.f) + (sg > 1 ? segs[1][j] : 0.f) +
              (sg > 2 ? segs[2][j] : 0.f);
  float acc = off;
#pragma unroll
  for (int i = 0; i < 16; ++i) {
    acc += laT[j * 65 + sg * 16 + i];
    cs[(size_t)(m0 + sg * 16 + i) * 64 + j] = acc;
  }
}

// ---------------- per-chunk state via MFMA: stT[p][n] = sum_s v[s][p]*ksc[s][n] ----------------
__global__ __launch_bounds__(256) void states_mfma(
    const bf16* __restrict__ Bmb, const bf16* __restrict__ xc,
    const float* __restrict__ cs, bf16* __restrict__ st) {
  int bid = blockIdx.x;
  int c = bid & 63, h = (bid >> 6) & 63, b = bid >> 12;
  int m0 = b * SEQLEN + c * CHUNK;
  int tid = threadIdx.x, lane = tid & 63, w = tid >> 6;
  int lr = lane & 15, lg = lane >> 4;
  __shared__ bf16 vT[64 * 72];
  __shared__ bf16 kT[64 * 72];
  int s4 = tid >> 2, c16 = (tid & 3) * 16;
  float cstot = cs[(size_t)(m0 + 63) * 64 + h];
  float ws = expf(cstot - cs[(size_t)(m0 + s4) * 64 + h]);
  {
    union { bf16x8 v[2]; bf16 hh[16]; } u;
    const bf16x8* pv = (const bf16x8*)&xc[(size_t)(m0 + s4) * DINNER + h * 64 + c16];
    u.v[0] = pv[0]; u.v[1] = pv[1];
#pragma unroll
    for (int i = 0; i < 16; ++i) vT[(c16 + i) * 72 + s4] = u.hh[i];
    const bf16x8* pk = (const bf16x8*)&Bmb[(size_t)(m0 + s4) * 64 + c16];
    u.v[0] = pk[0]; u.v[1] = pk[1];
#pragma unroll
    for (int i = 0; i < 16; ++i) kT[(c16 + i) * 72 + s4] = __float2bfloat16(to_f(u.hh[i]) * ws);
  }
  __syncthreads();
  f32x4 acc[4];
#pragma unroll
  for (int ct = 0; ct < 4; ++ct) acc[ct] = (f32x4){0.f, 0.f, 0.f, 0.f};
#pragma unroll
  for (int ks = 0; ks < 2; ++ks) {
    bf16x8 af = *(const bf16x8*)&vT[(w * 16 + lr) * 72 + ks * 32 + lg * 8];
#pragma unroll
    for (int ct = 0; ct < 4; ++ct) {
      bf16x8 bf_ = *(const bf16x8*)&kT[(ct * 16 + lr) * 72 + ks * 32 + lg * 8];
      acc[ct] = __builtin_amdgcn_mfma_f32_16x16x32_bf16(af, bf_, acc[ct], 0, 0, 0);
    }
  }
  size_t ob = (((size_t)(b * NHEADS + h)) * NCHUNK + c) * 4096;
#pragma unroll
  for (int ct = 0; ct < 4; ++ct) {
    int n = ct * 16 + lr;
#pragma unroll
    for (int r = 0; r < 4; ++r) {
      int p = w * 16 + lg * 4 + r;
      from_f(st[ob + (size_t)p * 64 + n], acc[ct][r]);
    }
  }
}

// ---------------- sequential scan over chunks; dec[] staged, ring-4 prefetch --
__global__ __launch_bounds__(256) void scan_kernel(
    const float* __restrict__ cs, bf16* __restrict__ st) {
  int bid = blockIdx.x;
  int bh = bid >> 2, qq = bid & 3;
  int b = bh >> 6, h = bh & 63;
  int tid = threadIdx.x;
  __shared__ float dec[64];
  if (tid < 64)
    dec[tid] = expf(cs[(size_t)(b * SEQLEN + tid * CHUNK + 63) * 64 + h]);
  int e0 = qq * 1024 + tid * 4;
  float hr[4] = {0.f, 0.f, 0.f, 0.f};
  size_t base = (size_t)bh * NCHUNK * 4096;
  typedef __attribute__((ext_vector_type(4))) short bf16x4;
  union U { bf16x4 v; bf16 hh[4]; };
  U buf[4];
  buf[0].v = *(bf16x4*)(st + base + 0 * 4096 + e0);
  buf[1].v = *(bf16x4*)(st + base + 1 * 4096 + e0);
  buf[2].v = *(bf16x4*)(st + base + 2 * 4096 + e0);
  __syncthreads();
#pragma unroll 4
  for (int c = 0; c < NCHUNK; ++c) {
    if (c + 3 < NCHUNK)
      buf[(c + 3) & 3].v = *(bf16x4*)(st + base + (size_t)(c + 3) * 4096 + e0);
    float d = dec[c];
    U out;
#pragma unroll
    for (int i = 0; i < 4; ++i) {
      float sv = to_f(buf[c & 3].hh[i]);
      from_f(out.hh[i], hr[i]);
      hr[i] = d * hr[i] + sv;
    }
    *(bf16x4*)(st + base + (size_t)c * 4096 + e0) = out.v;
  }
}

// ---------------- per-chunk output via MFMA ----------------
__global__ __launch_bounds__(256) void chunk_out_mfma(
    const bf16* __restrict__ Bmb, const bf16* __restrict__ Cmb,
    const bf16* __restrict__ xc, const float* __restrict__ cs,
    const bf16* __restrict__ st, const float* __restrict__ Dp,
    bf16* __restrict__ zx) {
  int bid = blockIdx.x;
  int c = bid & 63, h = (bid >> 6) & 63, b = bid >> 12;
  int m0 = b * SEQLEN + c * CHUNK;
  int tid = threadIdx.x, lane = tid & 63, w = tid >> 6;
  int lr = lane & 15, lg = lane >> 4;
  __shared__ bf16 qL[64 * 72];
  __shared__ bf16 kL[64 * 72];
  __shared__ bf16 A2[64 * 136];
  __shared__ bf16 B2[64 * 136];
  __shared__ float csl[64];
  int s4 = tid >> 2, c16 = (tid & 3) * 16;

  if (tid < 64) csl[tid] = cs[(size_t)(m0 + tid) * 64 + h];
  {
    const bf16x8* pq = (const bf16x8*)&Cmb[(size_t)(m0 + s4) * 64 + c16];
    *(bf16x8*)&qL[s4 * 72 + c16] = pq[0];
    *(bf16x8*)&qL[s4 * 72 + c16 + 8] = pq[1];
    const bf16x8* pk = (const bf16x8*)&Bmb[(size_t)(m0 + s4) * 64 + c16];
    *(bf16x8*)&kL[s4 * 72 + c16] = pk[0];
    *(bf16x8*)&kL[s4 * 72 + c16 + 8] = pk[1];
  }
  {
    union { bf16x8 v[2]; bf16 hh[16]; } u;
    const bf16x8* pv = (const bf16x8*)&xc[(size_t)(m0 + s4) * DINNER + h * 64 + c16];
    u.v[0] = pv[0]; u.v[1] = pv[1];
#pragma unroll
    for (int i = 0; i < 16; ++i) B2[(c16 + i) * 136 + s4] = u.hh[i];
  }
  {
    size_t hb = (((size_t)(b * NHEADS + h)) * NCHUNK + c) * 4096;
    const bf16x8* ph = (const bf16x8*)&st[hb + (size_t)s4 * 64 + c16];
    *(bf16x8*)&B2[s4 * 136 + 64 + c16] = ph[0];
    *(bf16x8*)&B2[s4 * 136 + 64 + c16 + 8] = ph[1];
  }
  __syncthreads();

  f32x4 acc1[4];
#pragma unroll
  for (int ct = 0; ct < 4; ++ct) acc1[ct] = (f32x4){0.f, 0.f, 0.f, 0.f};
#pragma unroll
  for (int ks = 0; ks < 2; ++ks) {
    bf16x8 af = *(const bf16x8*)&qL[(w * 16 + lr) * 72 + ks * 32 + lg * 8];
#pragma unroll
    for (int ct = 0; ct < 4; ++ct) {
      bf16x8 bf_ = *(const bf16x8*)&kL[(ct * 16 + lr) * 72 + ks * 32 + lg * 8];
      acc1[ct] = __builtin_amdgcn_mfma_f32_16x16x32_bf16(af, bf_, acc1[ct], 0, 0, 0);
    }
  }
  {
    float es = expf(csl[s4]);
    union { bf16x8 v[2]; bf16 hh[16]; } u;
    const bf16x8* pq = (const bf16x8*)&qL[s4 * 72 + c16];
    u.v[0] = pq[0]; u.v[1] = pq[1];
#pragma unroll
    for (int i = 0; i < 16; ++i) u.hh[i] = __float2bfloat16(to_f(u.hh[i]) * es);
    *(bf16x8*)&A2[s4 * 136 + 64 + c16] = u.v[0];
    *(bf16x8*)&A2[s4 * 136 + 64 + c16 + 8] = u.v[1];
  }
#pragma unroll
  for (int ct = 0; ct < 4; ++ct) {
    int t = ct * 16 + lr;
#pragma unroll
    for (int r = 0; r < 4; ++r) {
      int s = w * 16 + lg * 4 + r;
      float val = (t <= s) ? acc1[ct][r] * expf(csl[s] - csl[t]) : 0.f;
      A2[s * 136 + t] = __float2bfloat16(val);
    }
  }
  __syncthreads();

  float Dh = Dp[h];
  f32x4 acc2[4];
#pragma unroll
  for (int ct = 0; ct < 4; ++ct) {
    int p = ct * 16 + lr;
#pragma unroll
    for (int r = 0; r < 4; ++r)
      acc2[ct][r] = Dh * to_f(B2[p * 136 + (w * 16 + lg * 4 + r)]);
  }
#pragma unroll
  for (int ks = 0; ks < 4; ++ks) {
    bf16x8 af = *(const bf16x8*)&A2[(w * 16 + lr) * 136 + ks * 32 + lg * 8];
#pragma unroll
    for (int ct = 0; ct < 4; ++ct) {
      bf16x8 bf_ = *(const bf16x8*)&B2[(ct * 16 + lr) * 136 + ks * 32 + lg * 8];
      acc2[ct] = __builtin_amdgcn_mfma_f32_16x16x32_bf16(af, bf_, acc2[ct], 0, 0, 0);
    }
  }
  __syncthreads();
#pragma unroll
  for (int ct = 0; ct < 4; ++ct) {
    int p = ct * 16 + lr;
#pragma unroll
    for (int r = 0; r < 4; ++r)
      qL[(w * 16 + lg * 4 + r) * 72 + p] = __float2bfloat16(acc2[ct][r]);
  }
  __syncthreads();
  {
    const bf16x8* py = (const bf16x8*)&qL[s4 * 72 + c16];
    bf16x8* pg = (bf16x8*)&zx[(size_t)(m0 + s4) * DPROJ + DINNER + h * 64 + c16];
    pg[0] = py[0]; pg[1] = py[1];
  }
}

// ---------------- RMSNorm over 4096 + silu(z) gate, bf16x8 ----------------
__global__ __launch_bounds__(256) void rmsnorm_gate_kernel(
    bf16* __restrict__ zx, const float* __restrict__ scale) {
  int m = blockIdx.x;
  int tid = threadIdx.x;
  bf16* row = zx + (size_t)m * DPROJ;
  float vals[16];
  float ss = 0.f;
#pragma unroll
  for (int g = 0; g < 2; ++g) {
    int d8 = (tid + g * 256) * 8;
    bf16x8 yv = *(const bf16x8*)&row[DINNER + d8];
#pragma unroll
    for (int j = 0; j < 8; ++j) {
      float y = bf2f(yv[j]);
      vals[g * 8 + j] = y;
      ss += y * y;
    }
  }
#pragma unroll
  for (int off = 32; off > 0; off >>= 1) ss += __shfl_down(ss, off, 64);
  __shared__ float red[4];
  if ((tid & 63) == 0) red[tid >> 6] = ss;
  __syncthreads();
  float tot = red[0] + red[1] + red[2] + red[3];
  float inv = rsqrtf(tot / (float)DINNER + RMS_EPS);
#pragma unroll
  for (int g = 0; g < 2; ++g) {
    int d8 = (tid + g * 256) * 8;
    bf16x8 zv = *(const bf16x8*)&row[d8];
    const float* sc = scale + d8;
    bf16x8 o;
#pragma unroll
    for (int j = 0; j < 8; ++j) {
      bf16 hh = __float2bfloat16(vals[g * 8 + j] * inv * sc[j] * siluf(bf2f(zv[j])));
      o[j] = *(short*)&hh;
    }
    *(bf16x8*)&row[DINNER + d8] = o;
  }
}

// ---------------- launch ----------------
extern "C" void kernel_launch(void* const* d_in, const int* in_sizes, int n_in,
                              void* d_out, int out_size, void* d_ws, size_t ws_size,
                              hipStream_t stream) {
  const float* u       = (const float*)d_in[0];
  const float* Win     = (const float*)d_in[1];
  const float* cw      = (const float*)d_in[2];
  const float* cb      = (const float*)d_in[3];
  const float* A_log   = (const float*)d_in[4];
  const float* dt_bias = (const float*)d_in[5];
  const float* Dp      = (const float*)d_in[6];
  const float* nscale  = (const float*)d_in[7];
  const float* Wout    = (const float*)d_in[8];
  float* out = (float*)d_out;

  bf16* zx = (bf16*)d_ws;
  bf16* xc = zx + (size_t)MTOK * DPROJ;
  bf16* ub = xc;                                  // overlay: ub dead before xc written
  bf16* wT = xc + (size_t)MTOK * DINNER;
  bf16* Bmb = wT + (size_t)DPROJ_PAD * DMODEL;
  bf16* Cmb = Bmb + (size_t)MTOK * 64;
  float* cs = (float*)(Cmb + (size_t)MTOK * 64);
  bf16* st = (bf16*)d_out;                        // chunk states, 64 MiB

  cast_bf16_kernel<<<(MTOK * DMODEL) / (256 * 4), 256, 0, stream>>>(u, ub);
  transpose_cast_kernel<<<dim3(DPROJ_PAD / 32, DMODEL / 32), 256, 0, stream>>>(Win, wT, DPROJ, DMODEL);
  // 1a) in-projection z|x columns: N=8192, period-2 16-wave kernel, grid 1024
  gemm_w16p2<bf16, DMODEL / 32><<<(2 * DINNER / 256) * (MTOK / 256), 1024, 0, stream>>>(
      ub, DMODEL, wT, DMODEL, zx, DPROJ, 2 * DINNER / 256);
  // 1b) in-projection BCdt columns: N=192 (pad 256), 128x128 kernel
  gemm_mfma<bf16, true><<<dim3(2, MTOK / 128), 256, 0, stream>>>(
      ub, DMODEL, wT + (size_t)(2 * DINNER) * DMODEL, DMODEL,
      zx + 2 * DINNER, DPROJ, DMODEL, 192);
  transpose_cast_kernel<<<dim3(DMODEL / 32, DINNER / 32), 256, 0, stream>>>(Wout, wT, DMODEL, DINNER);
  conv_silu_kernel<<<(MTOK / 4) * 512 / 256, 256, 0, stream>>>(zx, cw, cb, xc);
  prep_cumsum_kernel<<<BATCH * NCHUNK, 256, 0, stream>>>(zx, A_log, dt_bias, Bmb, Cmb, cs);
  states_mfma<<<BATCH * NHEADS * NCHUNK, 256, 0, stream>>>(Bmb, xc, cs, st);
  scan_kernel<<<BATCH * NHEADS * 4, 256, 0, stream>>>(cs, st);
  chunk_out_mfma<<<BATCH * NHEADS * NCHUNK, 256, 0, stream>>>(Bmb, Cmb, xc, cs, st, Dp, zx);
  rmsnorm_gate_kernel<<<MTOK, 256, 0, stream>>>(zx, nscale);
  // 9) out-projection: period-2 16-wave kernel, float out, grid 256, KT=128
  gemm_w16p2<float, DINNER / 32><<<(DMODEL / 256) * (MTOK / 256), 1024, 0, stream>>>(
      zx + DINNER, DPROJ, wT, DINNER, out, DMODEL, DMODEL / 256);
}

// Round 17
// 635.190 us; speedup vs baseline: 1.1623x; 1.0003x over previous
//
#include <hip/hip_runtime.h>
#include <hip/hip_bf16.h>
#include <cstdint>
#include <cstddef>

// ---------------- problem constants ----------------
#define BATCH   2
#define SEQLEN  4096
#define DMODEL  2048
#define DINNER  4096
#define NHEADS  64
#define HEADDIM 64
#define DSTATE  64
#define CHUNK   64
#define NCHUNK  (SEQLEN/CHUNK)      // 64
#define DPROJ   8384
#define DPROJ_PAD 8448
#define MTOK    (BATCH*SEQLEN)      // 8192
#define RMS_EPS 1e-6f

typedef __hip_bfloat16 bf16;
typedef __attribute__((ext_vector_type(8))) short bf16x8;
typedef __attribute__((ext_vector_type(4))) float f32x4;

__device__ __forceinline__ float siluf(float x) { return x / (1.f + expf(-x)); }
__device__ __forceinline__ float to_f(float x) { return x; }
__device__ __forceinline__ float to_f(bf16 x) { return __bfloat162float(x); }
__device__ __forceinline__ float bf2f(short s) { bf16 h; *(short*)&h = s; return __bfloat162float(h); }
__device__ __forceinline__ void from_f(float& d, float x) { d = x; }
__device__ __forceinline__ void from_f(bf16& d, float x) { d = __float2bfloat16(x); }

__device__ __forceinline__ void gload16(const void* g, void* l) {
  __builtin_amdgcn_global_load_lds(
      (const __attribute__((address_space(1))) void*)g,
      (__attribute__((address_space(3))) void*)l, 16, 0, 0);
}

// ---------------- gemm_w16: 256x256 tile, 16 waves, per-tile barrier ---------
// (round-13 verified variant — best measured for KT=64)
template <typename TC, int KT>
__global__ __launch_bounds__(1024, 4) void gemm_w16(
    const bf16* __restrict__ A, int lda,
    const bf16* __restrict__ BT, int ldb,
    TC* __restrict__ C, int ldc, int gx) {
  __shared__ __align__(16) bf16 As[4 * 8192];
  __shared__ __align__(16) bf16 Bs[4 * 8192];
  const int tid  = threadIdx.x;
  const int lane = tid & 63;
  const int w    = tid >> 6;
  const int wm   = w >> 2;
  const int wn   = w & 3;
  const int lr   = lane & 15, lg = lane >> 4;
  const int fo   = 8 * (lg ^ ((lr >> 1) & 3));

  int nwg = gridDim.x;
  int bid = (int)blockIdx.x;
  int idx = (bid & 7) * (nwg >> 3) + (bid >> 3);
  int spos = idx % (8 * gx);
  const int m0 = ((idx / (8 * gx)) * 8 + (spos & 7)) * 256;
  const int n0 = (spos >> 3) * 256;

  const int srow = tid >> 2;
  const int ce   = 8 * ((tid & 3) ^ ((tid >> 3) & 3));
  const bf16* pA = A  + (size_t)(m0 + srow) * lda + ce;
  const bf16* pB = BT + (size_t)(n0 + srow) * ldb + ce;
  const int wofs = w * 512;
  const int aRd = (wm * 64 + lr) * 32 + fo;
  const int bRd = (wn * 64 + lr) * 32 + fo;

#define STAGE_A(kt) gload16(pA + ((kt) << 5), As + (((kt) & 3) << 13) + wofs)
#define STAGE_B(kt) gload16(pB + ((kt) << 5), Bs + (((kt) & 3) << 13) + wofs)

  f32x4 acc[4][4];
#pragma unroll
  for (int m = 0; m < 4; ++m)
#pragma unroll
    for (int n = 0; n < 4; ++n) acc[m][n] = (f32x4){0.f, 0.f, 0.f, 0.f};

#define KBODY(T, DOSTAGE, VMC) do {                                          \
    const bf16* Ab = As + (((T) & 3) << 13);                                 \
    const bf16* Bb = Bs + (((T) & 3) << 13);                                 \
    if (DOSTAGE) { STAGE_A((T) + 3); STAGE_B((T) + 3); }                     \
    bf16x8 bfv[4], af[4];                                                    \
    _Pragma("unroll")                                                        \
    for (int n = 0; n < 4; ++n) bfv[n] = *(const bf16x8*)&Bb[bRd + n * 512]; \
    _Pragma("unroll")                                                        \
    for (int m = 0; m < 4; ++m) af[m] = *(const bf16x8*)&Ab[aRd + m * 512];  \
    asm volatile("s_waitcnt lgkmcnt(0)" ::: "memory");                       \
    __builtin_amdgcn_sched_barrier(0);                                       \
    __builtin_amdgcn_s_setprio(1);                                           \
    _Pragma("unroll")                                                        \
    for (int m = 0; m < 4; ++m)                                              \
      _Pragma("unroll")                                                      \
      for (int n = 0; n < 4; ++n)                                            \
        acc[m][n] = __builtin_amdgcn_mfma_f32_16x16x32_bf16(af[m], bfv[n], acc[m][n], 0, 0, 0); \
    __builtin_amdgcn_s_setprio(0);                                           \
    asm volatile("s_waitcnt vmcnt(" #VMC ")" ::: "memory");                  \
    __builtin_amdgcn_s_barrier();                                            \
    __builtin_amdgcn_sched_barrier(0);                                       \
  } while (0)

  STAGE_A(0); STAGE_B(0); STAGE_A(1); STAGE_B(1); STAGE_A(2); STAGE_B(2);
  asm volatile("s_waitcnt vmcnt(4)" ::: "memory");
  __builtin_amdgcn_s_barrier();
  __builtin_amdgcn_sched_barrier(0);

#pragma unroll 4
  for (int t = 0; t < KT - 3; ++t) KBODY(t, true, 4);
  KBODY(KT - 3, false, 2);
  KBODY(KT - 2, false, 0);
  KBODY(KT - 1, false, 0);
#undef KBODY
#undef STAGE_A
#undef STAGE_B

  if constexpr (__is_same(TC, bf16)) {
    bf16* Ws = (w < 8 ? As : Bs) + (w & 7) * 4096;
#pragma unroll
    for (int m = 0; m < 4; ++m)
#pragma unroll
      for (int n = 0; n < 4; ++n)
#pragma unroll
        for (int reg = 0; reg < 4; ++reg) {
          int row = m * 16 + lg * 4 + reg;
          int slot = (n * 2 + (lr >> 3)) ^ (row & 7);
          Ws[row * 64 + slot * 8 + (lr & 7)] = __float2bfloat16(acc[m][n][reg]);
        }
    asm volatile("s_waitcnt lgkmcnt(0)" ::: "memory");
#pragma unroll
    for (int i = 0; i < 8; ++i) {
      int row = i * 8 + (lane >> 3);
      bf16x8 v = *(const bf16x8*)&Ws[row * 64 + ((lane & 7) ^ (lane >> 3)) * 8];
      int gcol = n0 + wn * 64 + (lane & 7) * 8;
      *(bf16x8*)&((bf16*)C)[(size_t)(m0 + wm * 64 + row) * ldc + gcol] = v;
    }
  } else {
#pragma unroll
    for (int m = 0; m < 4; ++m)
#pragma unroll
      for (int n = 0; n < 4; ++n) {
        int col = n0 + wn * 64 + n * 16 + lr;
        size_t rbase = (size_t)(m0 + wm * 64 + m * 16 + lg * 4);
#pragma unroll
        for (int reg = 0; reg < 4; ++reg)
          from_f(C[(rbase + reg) * ldc + col], acc[m][n][reg]);
      }
  }
}

// ---------------- gemm_w16p2: period-2 variant (best for KT=128 out-proj) ----
template <typename TC, int KT>
__global__ __launch_bounds__(1024, 4) void gemm_w16p2(
    const bf16* __restrict__ A, int lda,
    const bf16* __restrict__ BT, int ldb,
    TC* __restrict__ C, int ldc, int gx) {
  __shared__ __align__(16) bf16 As[4 * 8192];
  __shared__ __align__(16) bf16 Bs[4 * 8192];
  const int tid  = threadIdx.x;
  const int lane = tid & 63;
  const int w    = tid >> 6;
  const int wm   = w >> 2;
  const int wn   = w & 3;
  const int lr   = lane & 15, lg = lane >> 4;
  const int fo   = 8 * (lg ^ ((lr >> 1) & 3));

  int nwg = gridDim.x;
  int bid = (int)blockIdx.x;
  int idx = (bid & 7) * (nwg >> 3) + (bid >> 3);
  int spos = idx % (8 * gx);
  const int m0 = ((idx / (8 * gx)) * 8 + (spos & 7)) * 256;
  const int n0 = (spos >> 3) * 256;

  const int srow = tid >> 2;
  const int ce   = 8 * ((tid & 3) ^ ((tid >> 3) & 3));
  const bf16* pA = A  + (size_t)(m0 + srow) * lda + ce;
  const bf16* pB = BT + (size_t)(n0 + srow) * ldb + ce;
  const int wofs = w * 512;
  const int aRd = (wm * 64 + lr) * 32 + fo;
  const int bRd = (wn * 64 + lr) * 32 + fo;

#define STAGE_A(kt) gload16(pA + ((kt) << 5), As + (((kt) & 3) << 13) + wofs)
#define STAGE_B(kt) gload16(pB + ((kt) << 5), Bs + (((kt) & 3) << 13) + wofs)

  f32x4 acc[4][4];
#pragma unroll
  for (int m = 0; m < 4; ++m)
#pragma unroll
    for (int n = 0; n < 4; ++n) acc[m][n] = (f32x4){0.f, 0.f, 0.f, 0.f};

#define TILE(T) do {                                                         \
    const bf16* Ab = As + (((T) & 3) << 13);                                 \
    const bf16* Bb = Bs + (((T) & 3) << 13);                                 \
    bf16x8 bfv[4], af[4];                                                    \
    _Pragma("unroll")                                                        \
    for (int n = 0; n < 4; ++n) bfv[n] = *(const bf16x8*)&Bb[bRd + n * 512]; \
    _Pragma("unroll")                                                        \
    for (int m = 0; m < 4; ++m) af[m] = *(const bf16x8*)&Ab[aRd + m * 512];  \
    asm volatile("s_waitcnt lgkmcnt(0)" ::: "memory");                       \
    __builtin_amdgcn_sched_barrier(0);                                       \
    __builtin_amdgcn_s_setprio(1);                                           \
    _Pragma("unroll")                                                        \
    for (int m = 0; m < 4; ++m)                                              \
      _Pragma("unroll")                                                      \
      for (int n = 0; n < 4; ++n)                                            \
        acc[m][n] = __builtin_amdgcn_mfma_f32_16x16x32_bf16(af[m], bfv[n], acc[m][n], 0, 0, 0); \
    __builtin_amdgcn_s_setprio(0);                                           \
  } while (0)

#define PERIOD(P, DOSTAGE) do {                                              \
    if (DOSTAGE) { STAGE_A(2 * (P) + 2); STAGE_B(2 * (P) + 2);               \
                   STAGE_A(2 * (P) + 3); STAGE_B(2 * (P) + 3); }             \
    TILE(2 * (P));                                                           \
    TILE(2 * (P) + 1);                                                       \
    asm volatile("s_waitcnt vmcnt(0)" ::: "memory");                         \
    __builtin_amdgcn_s_barrier();                                            \
    __builtin_amdgcn_sched_barrier(0);                                       \
  } while (0)

  STAGE_A(0); STAGE_B(0); STAGE_A(1); STAGE_B(1);
  asm volatile("s_waitcnt vmcnt(0)" ::: "memory");
  __builtin_amdgcn_s_barrier();
  __builtin_amdgcn_sched_barrier(0);

  const int NP = KT / 2;
#pragma unroll 2
  for (int p = 0; p < NP - 1; ++p) PERIOD(p, true);
  PERIOD(NP - 1, false);
#undef PERIOD
#undef TILE
#undef STAGE_A
#undef STAGE_B

  if constexpr (__is_same(TC, bf16)) {
    bf16* Ws = (w < 8 ? As : Bs) + (w & 7) * 4096;
#pragma unroll
    for (int m = 0; m < 4; ++m)
#pragma unroll
      for (int n = 0; n < 4; ++n)
#pragma unroll
        for (int reg = 0; reg < 4; ++reg) {
          int row = m * 16 + lg * 4 + reg;
          int slot = (n * 2 + (lr >> 3)) ^ (row & 7);
          Ws[row * 64 + slot * 8 + (lr & 7)] = __float2bfloat16(acc[m][n][reg]);
        }
    asm volatile("s_waitcnt lgkmcnt(0)" ::: "memory");
#pragma unroll
    for (int i = 0; i < 8; ++i) {
      int row = i * 8 + (lane >> 3);
      bf16x8 v = *(const bf16x8*)&Ws[row * 64 + ((lane & 7) ^ (lane >> 3)) * 8];
      int gcol = n0 + wn * 64 + (lane & 7) * 8;
      *(bf16x8*)&((bf16*)C)[(size_t)(m0 + wm * 64 + row) * ldc + gcol] = v;
    }
  } else {
#pragma unroll
    for (int m = 0; m < 4; ++m)
#pragma unroll
      for (int n = 0; n < 4; ++n) {
        int col = n0 + wn * 64 + n * 16 + lr;
        size_t rbase = (size_t)(m0 + wm * 64 + m * 16 + lg * 4);
#pragma unroll
        for (int reg = 0; reg < 4; ++reg)
          from_f(C[(rbase + reg) * ldc + col], acc[m][n][reg]);
      }
  }
}

// ---------------- gemm_bcdt: 32x128 tile, 2 waves — narrow-N high-TLP GEMM ---
// C[M,N] = A[M,K] @ BT[N,K]^T for N<=256.  128 thr = 2 waves (wave w owns
// cols w*64..w*64+63); acc[2][4] (32 f32).  LDS 10 KB -> 2+ blocks/CU at
// grid 512; single-buffered 2-barrier loop (cross-block TLP hides latency).
// Swizzle identical to the verified round-4 kernel (key = row&3 both sides).
template <typename TC>
__global__ __launch_bounds__(128) void gemm_bcdt(
    const bf16* __restrict__ A, int lda,
    const bf16* __restrict__ BT, int ldb,
    TC* __restrict__ C, int ldc, int Kdim, int Nvalid) {
  __shared__ __align__(16) bf16 As[32 * 32];    // 2 KB
  __shared__ __align__(16) bf16 Bs[128 * 32];   // 8 KB
  const int tid  = threadIdx.x;
  const int lane = tid & 63;
  const int w    = tid >> 6;          // 0..1
  const int lr   = lane & 15, lg = lane >> 4;
  const int fo   = 8 * (lg ^ (lr & 3));
  const int m0 = blockIdx.y * 32;
  const int n0 = blockIdx.x * 128;

  const int srow = tid >> 2;                           // 0..31
  const int ce   = 8 * ((tid & 3) ^ ((tid >> 2) & 3)); // swizzled k-elem
  const bf16* pA = A  + (size_t)(m0 + srow) * lda + ce;
  const bf16* pB = BT + (size_t)(n0 + srow) * ldb + ce;
  const int dof = w * 512;            // wave w covers rows w*16.. per gload

  f32x4 acc[2][4];
#pragma unroll
  for (int m = 0; m < 2; ++m)
#pragma unroll
    for (int n = 0; n < 4; ++n) acc[m][n] = (f32x4){0.f, 0.f, 0.f, 0.f};

  for (int k0 = 0; k0 < Kdim; k0 += 32) {
    __syncthreads();                  // prior reads done before overwrite
    gload16(pA + k0, As + dof);
    gload16(pB + k0,                   Bs + 0 * 1024 + dof);
    gload16(pB + (size_t)32 * ldb + k0, Bs + 1 * 1024 + dof);
    gload16(pB + (size_t)64 * ldb + k0, Bs + 2 * 1024 + dof);
    gload16(pB + (size_t)96 * ldb + k0, Bs + 3 * 1024 + dof);
    __syncthreads();                  // implies vmcnt(0) drain -> tiles ready
    bf16x8 af[2], bfr[4];
#pragma unroll
    for (int m = 0; m < 2; ++m)
      af[m] = *(const bf16x8*)&As[(m * 16 + lr) * 32 + fo];
#pragma unroll
    for (int n = 0; n < 4; ++n)
      bfr[n] = *(const bf16x8*)&Bs[(w * 64 + n * 16 + lr) * 32 + fo];
#pragma unroll
    for (int m = 0; m < 2; ++m)
#pragma unroll
      for (int n = 0; n < 4; ++n)
        acc[m][n] = __builtin_amdgcn_mfma_f32_16x16x32_bf16(af[m], bfr[n], acc[m][n], 0, 0, 0);
  }

#pragma unroll
  for (int m = 0; m < 2; ++m)
#pragma unroll
    for (int n = 0; n < 4; ++n) {
      int col = n0 + w * 64 + n * 16 + lr;
      if (col >= Nvalid) continue;
      size_t rbase = (size_t)(m0 + m * 16 + lg * 4);
#pragma unroll
      for (int reg = 0; reg < 4; ++reg)
        from_f(C[(rbase + reg) * ldc + col], acc[m][n][reg]);
    }
}

// ---------------- cast fp32 -> bf16 (4/thread) ----------------
__global__ __launch_bounds__(256) void cast_bf16_kernel(
    const float* __restrict__ x, bf16* __restrict__ y) {
  size_t i = ((size_t)blockIdx.x * 256 + threadIdx.x) * 4;
  float4 v = *(const float4*)(x + i);
  y[i + 0] = __float2bfloat16(v.x);
  y[i + 1] = __float2bfloat16(v.y);
  y[i + 2] = __float2bfloat16(v.z);
  y[i + 3] = __float2bfloat16(v.w);
}

// ---------------- transpose + cast: WT[Npad][K] = W[K][N]^T ----------------
__global__ __launch_bounds__(256) void transpose_cast_kernel(
    const float* __restrict__ W, bf16* __restrict__ WT, int N, int K) {
  __shared__ float t[32][33];
  int n0 = blockIdx.x * 32, k0 = blockIdx.y * 32;
  int tx = threadIdx.x & 31, ty = threadIdx.x >> 5;
#pragma unroll
  for (int i = 0; i < 4; ++i) {
    int n = n0 + tx;
    t[ty + i * 8][tx] = (n < N) ? W[(size_t)(k0 + ty + i * 8) * N + n] : 0.f;
  }
  __syncthreads();
#pragma unroll
  for (int i = 0; i < 4; ++i) {
    int nn = ty + i * 8;
    WT[(size_t)(n0 + nn) * K + k0 + tx] = __float2bfloat16(t[tx][nn]);
  }
}

// ---------------- depthwise causal conv1d (K=4) + SiLU, 4 tokens/thread ------
__global__ __launch_bounds__(256) void conv_silu_kernel(
    const bf16* __restrict__ zx, const float* __restrict__ cw,
    const float* __restrict__ cb, bf16* __restrict__ xc) {
  int idx = blockIdx.x * 256 + threadIdx.x;
  int d8 = (idx & 511) * 8;
  int g = idx >> 9;
  int m0 = g * 4;
  int l0 = m0 & (SEQLEN - 1);
  int b = m0 >> 12;
  bf16x8 rows[7];
  bf16x8 zvec;
#pragma unroll
  for (int j = 0; j < 8; ++j) zvec[j] = 0;
#pragma unroll
  for (int r = 0; r < 7; ++r) {
    int li = l0 - 3 + r;
    rows[r] = (li >= 0)
        ? *(const bf16x8*)&zx[(size_t)(b * SEQLEN + li) * DPROJ + DINNER + d8]
        : zvec;
  }
  float cwv[4][8], cbv[8];
#pragma unroll
  for (int k = 0; k < 4; ++k) {
    float4 a = *(const float4*)(cw + k * DINNER + d8);
    float4 bb = *(const float4*)(cw + k * DINNER + d8 + 4);
    cwv[k][0] = a.x; cwv[k][1] = a.y; cwv[k][2] = a.z; cwv[k][3] = a.w;
    cwv[k][4] = bb.x; cwv[k][5] = bb.y; cwv[k][6] = bb.z; cwv[k][7] = bb.w;
  }
  {
    float4 a = *(const float4*)(cb + d8);
    float4 bb = *(const float4*)(cb + d8 + 4);
    cbv[0] = a.x; cbv[1] = a.y; cbv[2] = a.z; cbv[3] = a.w;
    cbv[4] = bb.x; cbv[5] = bb.y; cbv[6] = bb.z; cbv[7] = bb.w;
  }
#pragma unroll
  for (int j = 0; j < 4; ++j) {
    float acc[8];
#pragma unroll
    for (int e = 0; e < 8; ++e) acc[e] = cbv[e];
#pragma unroll
    for (int k = 0; k < 4; ++k)
#pragma unroll
      for (int e = 0; e < 8; ++e) acc[e] += bf2f(rows[j + k][e]) * cwv[k][e];
    bf16x8 o;
#pragma unroll
    for (int e = 0; e < 8; ++e) { bf16 h = __float2bfloat16(siluf(acc[e])); o[e] = *(short*)&h; }
    *(bf16x8*)&xc[(size_t)(m0 + j) * DINNER + d8] = o;
  }
}

// ---------------- fused B/C elu+1 + log-decay + per-chunk cumsum --------------
__global__ __launch_bounds__(256) void prep_cumsum_kernel(
    const bf16* __restrict__ zx, const float* __restrict__ A_log,
    const float* __restrict__ dt_bias, bf16* __restrict__ Bmb,
    bf16* __restrict__ Cmb, float* __restrict__ cs) {
  int bid = blockIdx.x;            // b*64 + c
  int c = bid & 63, b = bid >> 6;
  int m0 = b * SEQLEN + c * CHUNK;
  int tid = threadIdx.x;
  int s = tid >> 2, grp = (tid & 3) * 16;
  __shared__ float laT[64 * 65];
  __shared__ float segs[4][64];
  const bf16* row = zx + (size_t)(m0 + s) * DPROJ + 2 * DINNER;
  {
    union { bf16x8 v[2]; bf16 hh[16]; } u, o;
    u.v[0] = *(const bf16x8*)&row[grp];
    u.v[1] = *(const bf16x8*)&row[grp + 8];
#pragma unroll
    for (int i = 0; i < 16; ++i) {
      float bv = to_f(u.hh[i]);
      from_f(o.hh[i], bv > 0.f ? bv + 1.f : expf(bv));
    }
    *(bf16x8*)&Bmb[(size_t)(m0 + s) * 64 + grp] = o.v[0];
    *(bf16x8*)&Bmb[(size_t)(m0 + s) * 64 + grp + 8] = o.v[1];
    u.v[0] = *(const bf16x8*)&row[64 + grp];
    u.v[1] = *(const bf16x8*)&row[64 + grp + 8];
#pragma unroll
    for (int i = 0; i < 16; ++i) {
      float cv = to_f(u.hh[i]);
      from_f(o.hh[i], cv > 0.f ? cv + 1.f : expf(cv));
    }
    *(bf16x8*)&Cmb[(size_t)(m0 + s) * 64 + grp] = o.v[0];
    *(bf16x8*)&Cmb[(size_t)(m0 + s) * 64 + grp + 8] = o.v[1];
    u.v[0] = *(const bf16x8*)&row[128 + grp];
    u.v[1] = *(const bf16x8*)&row[128 + grp + 8];
#pragma unroll
    for (int i = 0; i < 16; ++i) {
      int j = grp + i;
      float dtl = to_f(u.hh[i]) + dt_bias[j];
      float dt = dtl > 20.f ? dtl : log1pf(expf(dtl));
      laT[j * 65 + s] = -dt * expf(A_log[j]);
    }
  }
  __syncthreads();
  int j = tid & 63, sg = tid >> 6;
  float p = 0.f;
#pragma unroll
  for (int i = 0; i < 16; ++i) p += laT[j * 65 + sg * 16 + i];
  segs[sg][j] = p;
  __syncthreads();
  float off = (sg > 0 ? segs[0][j] : 0.f) + (sg > 1 ? segs[1][j] : 0.f) +
              (sg > 2 ? segs[2][j] : 0.f);
  float acc = off;
#pragma unroll
  for (int i = 0; i < 16; ++i) {
    acc += laT[j * 65 + sg * 16 + i];
    cs[(size_t)(m0 + sg * 16 + i) * 64 + j] = acc;
  }
}

// ---------------- per-chunk state via MFMA: stT[p][n] = sum_s v[s][p]*ksc[s][n] ----------------
__global__ __launch_bounds__(256) void states_mfma(
    const bf16* __restrict__ Bmb, const bf16* __restrict__ xc,
    const float* __restrict__ cs, bf16* __restrict__ st) {
  int bid = blockIdx.x;
  int c = bid & 63, h = (bid >> 6) & 63, b = bid >> 12;
  int m0 = b * SEQLEN + c * CHUNK;
  int tid = threadIdx.x, lane = tid & 63, w = tid >> 6;
  int lr = lane & 15, lg = lane >> 4;
  __shared__ bf16 vT[64 * 72];
  __shared__ bf16 kT[64 * 72];
  int s4 = tid >> 2, c16 = (tid & 3) * 16;
  float cstot = cs[(size_t)(m0 + 63) * 64 + h];
  float ws = expf(cstot - cs[(size_t)(m0 + s4) * 64 + h]);
  {
    union { bf16x8 v[2]; bf16 hh[16]; } u;
    const bf16x8* pv = (const bf16x8*)&xc[(size_t)(m0 + s4) * DINNER + h * 64 + c16];
    u.v[0] = pv[0]; u.v[1] = pv[1];
#pragma unroll
    for (int i = 0; i < 16; ++i) vT[(c16 + i) * 72 + s4] = u.hh[i];
    const bf16x8* pk = (const bf16x8*)&Bmb[(size_t)(m0 + s4) * 64 + c16];
    u.v[0] = pk[0]; u.v[1] = pk[1];
#pragma unroll
    for (int i = 0; i < 16; ++i) kT[(c16 + i) * 72 + s4] = __float2bfloat16(to_f(u.hh[i]) * ws);
  }
  __syncthreads();
  f32x4 acc[4];
#pragma unroll
  for (int ct = 0; ct < 4; ++ct) acc[ct] = (f32x4){0.f, 0.f, 0.f, 0.f};
#pragma unroll
  for (int ks = 0; ks < 2; ++ks) {
    bf16x8 af = *(const bf16x8*)&vT[(w * 16 + lr) * 72 + ks * 32 + lg * 8];
#pragma unroll
    for (int ct = 0; ct < 4; ++ct) {
      bf16x8 bf_ = *(const bf16x8*)&kT[(ct * 16 + lr) * 72 + ks * 32 + lg * 8];
      acc[ct] = __builtin_amdgcn_mfma_f32_16x16x32_bf16(af, bf_, acc[ct], 0, 0, 0);
    }
  }
  size_t ob = (((size_t)(b * NHEADS + h)) * NCHUNK + c) * 4096;
#pragma unroll
  for (int ct = 0; ct < 4; ++ct) {
    int n = ct * 16 + lr;
#pragma unroll
    for (int r = 0; r < 4; ++r) {
      int p = w * 16 + lg * 4 + r;
      from_f(st[ob + (size_t)p * 64 + n], acc[ct][r]);
    }
  }
}

// ---------------- sequential scan over chunks; dec[] staged, ring-4 prefetch --
__global__ __launch_bounds__(256) void scan_kernel(
    const float* __restrict__ cs, bf16* __restrict__ st) {
  int bid = blockIdx.x;
  int bh = bid >> 2, qq = bid & 3;
  int b = bh >> 6, h = bh & 63;
  int tid = threadIdx.x;
  __shared__ float dec[64];
  if (tid < 64)
    dec[tid] = expf(cs[(size_t)(b * SEQLEN + tid * CHUNK + 63) * 64 + h]);
  int e0 = qq * 1024 + tid * 4;
  float hr[4] = {0.f, 0.f, 0.f, 0.f};
  size_t base = (size_t)bh * NCHUNK * 4096;
  typedef __attribute__((ext_vector_type(4))) short bf16x4;
  union U { bf16x4 v; bf16 hh[4]; };
  U buf[4];
  buf[0].v = *(bf16x4*)(st + base + 0 * 4096 + e0);
  buf[1].v = *(bf16x4*)(st + base + 1 * 4096 + e0);
  buf[2].v = *(bf16x4*)(st + base + 2 * 4096 + e0);
  __syncthreads();
#pragma unroll 4
  for (int c = 0; c < NCHUNK; ++c) {
    if (c + 3 < NCHUNK)
      buf[(c + 3) & 3].v = *(bf16x4*)(st + base + (size_t)(c + 3) * 4096 + e0);
    float d = dec[c];
    U out;
#pragma unroll
    for (int i = 0; i < 4; ++i) {
      float sv = to_f(buf[c & 3].hh[i]);
      from_f(out.hh[i], hr[i]);
      hr[i] = d * hr[i] + sv;
    }
    *(bf16x4*)(st + base + (size_t)c * 4096 + e0) = out.v;
  }
}

// ---------------- per-chunk output via MFMA ----------------
__global__ __launch_bounds__(256) void chunk_out_mfma(
    const bf16* __restrict__ Bmb, const bf16* __restrict__ Cmb,
    const bf16* __restrict__ xc, const float* __restrict__ cs,
    const bf16* __restrict__ st, const float* __restrict__ Dp,
    bf16* __restrict__ zx) {
  int bid = blockIdx.x;
  int c = bid & 63, h = (bid >> 6) & 63, b = bid >> 12;
  int m0 = b * SEQLEN + c * CHUNK;
  int tid = threadIdx.x, lane = tid & 63, w = tid >> 6;
  int lr = lane & 15, lg = lane >> 4;
  __shared__ bf16 qL[64 * 72];
  __shared__ bf16 kL[64 * 72];
  __shared__ bf16 A2[64 * 136];
  __shared__ bf16 B2[64 * 136];
  __shared__ float csl[64];
  int s4 = tid >> 2, c16 = (tid & 3) * 16;

  if (tid < 64) csl[tid] = cs[(size_t)(m0 + tid) * 64 + h];
  {
    const bf16x8* pq = (const bf16x8*)&Cmb[(size_t)(m0 + s4) * 64 + c16];
    *(bf16x8*)&qL[s4 * 72 + c16] = pq[0];
    *(bf16x8*)&qL[s4 * 72 + c16 + 8] = pq[1];
    const bf16x8* pk = (const bf16x8*)&Bmb[(size_t)(m0 + s4) * 64 + c16];
    *(bf16x8*)&kL[s4 * 72 + c16] = pk[0];
    *(bf16x8*)&kL[s4 * 72 + c16 + 8] = pk[1];
  }
  {
    union { bf16x8 v[2]; bf16 hh[16]; } u;
    const bf16x8* pv = (const bf16x8*)&xc[(size_t)(m0 + s4) * DINNER + h * 64 + c16];
    u.v[0] = pv[0]; u.v[1] = pv[1];
#pragma unroll
    for (int i = 0; i < 16; ++i) B2[(c16 + i) * 136 + s4] = u.hh[i];
  }
  {
    size_t hb = (((size_t)(b * NHEADS + h)) * NCHUNK + c) * 4096;
    const bf16x8* ph = (const bf16x8*)&st[hb + (size_t)s4 * 64 + c16];
    *(bf16x8*)&B2[s4 * 136 + 64 + c16] = ph[0];
    *(bf16x8*)&B2[s4 * 136 + 64 + c16 + 8] = ph[1];
  }
  __syncthreads();

  f32x4 acc1[4];
#pragma unroll
  for (int ct = 0; ct < 4; ++ct) acc1[ct] = (f32x4){0.f, 0.f, 0.f, 0.f};
#pragma unroll
  for (int ks = 0; ks < 2; ++ks) {
    bf16x8 af = *(const bf16x8*)&qL[(w * 16 + lr) * 72 + ks * 32 + lg * 8];
#pragma unroll
    for (int ct = 0; ct < 4; ++ct) {
      bf16x8 bf_ = *(const bf16x8*)&kL[(ct * 16 + lr) * 72 + ks * 32 + lg * 8];
      acc1[ct] = __builtin_amdgcn_mfma_f32_16x16x32_bf16(af, bf_, acc1[ct], 0, 0, 0);
    }
  }
  {
    float es = expf(csl[s4]);
    union { bf16x8 v[2]; bf16 hh[16]; } u;
    const bf16x8* pq = (const bf16x8*)&qL[s4 * 72 + c16];
    u.v[0] = pq[0]; u.v[1] = pq[1];
#pragma unroll
    for (int i = 0; i < 16; ++i) u.hh[i] = __float2bfloat16(to_f(u.hh[i]) * es);
    *(bf16x8*)&A2[s4 * 136 + 64 + c16] = u.v[0];
    *(bf16x8*)&A2[s4 * 136 + 64 + c16 + 8] = u.v[1];
  }
#pragma unroll
  for (int ct = 0; ct < 4; ++ct) {
    int t = ct * 16 + lr;
#pragma unroll
    for (int r = 0; r < 4; ++r) {
      int s = w * 16 + lg * 4 + r;
      float val = (t <= s) ? acc1[ct][r] * expf(csl[s] - csl[t]) : 0.f;
      A2[s * 136 + t] = __float2bfloat16(val);
    }
  }
  __syncthreads();

  float Dh = Dp[h];
  f32x4 acc2[4];
#pragma unroll
  for (int ct = 0; ct < 4; ++ct) {
    int p = ct * 16 + lr;
#pragma unroll
    for (int r = 0; r < 4; ++r)
      acc2[ct][r] = Dh * to_f(B2[p * 136 + (w * 16 + lg * 4 + r)]);
  }
#pragma unroll
  for (int ks = 0; ks < 4; ++ks) {
    bf16x8 af = *(const bf16x8*)&A2[(w * 16 + lr) * 136 + ks * 32 + lg * 8];
#pragma unroll
    for (int ct = 0; ct < 4; ++ct) {
      bf16x8 bf_ = *(const bf16x8*)&B2[(ct * 16 + lr) * 136 + ks * 32 + lg * 8];
      acc2[ct] = __builtin_amdgcn_mfma_f32_16x16x32_bf16(af, bf_, acc2[ct], 0, 0, 0);
    }
  }
  __syncthreads();
#pragma unroll
  for (int ct = 0; ct < 4; ++ct) {
    int p = ct * 16 + lr;
#pragma unroll
    for (int r = 0; r < 4; ++r)
      qL[(w * 16 + lg * 4 + r) * 72 + p] = __float2bfloat16(acc2[ct][r]);
  }
  __syncthreads();
  {
    const bf16x8* py = (const bf16x8*)&qL[s4 * 72 + c16];
    bf16x8* pg = (bf16x8*)&zx[(size_t)(m0 + s4) * DPROJ + DINNER + h * 64 + c16];
    pg[0] = py[0]; pg[1] = py[1];
  }
}

// ---------------- RMSNorm over 4096 + silu(z) gate, bf16x8 ----------------
__global__ __launch_bounds__(256) void rmsnorm_gate_kernel(
    bf16* __restrict__ zx, const float* __restrict__ scale) {
  int m = blockIdx.x;
  int tid = threadIdx.x;
  bf16* row = zx + (size_t)m * DPROJ;
  float vals[16];
  float ss = 0.f;
#pragma unroll
  for (int g = 0; g < 2; ++g) {
    int d8 = (tid + g * 256) * 8;
    bf16x8 yv = *(const bf16x8*)&row[DINNER + d8];
#pragma unroll
    for (int j = 0; j < 8; ++j) {
      float y = bf2f(yv[j]);
      vals[g * 8 + j] = y;
      ss += y * y;
    }
  }
#pragma unroll
  for (int off = 32; off > 0; off >>= 1) ss += __shfl_down(ss, off, 64);
  __shared__ float red[4];
  if ((tid & 63) == 0) red[tid >> 6] = ss;
  __syncthreads();
  float tot = red[0] + red[1] + red[2] + red[3];
  float inv = rsqrtf(tot / (float)DINNER + RMS_EPS);
#pragma unroll
  for (int g = 0; g < 2; ++g) {
    int d8 = (tid + g * 256) * 8;
    bf16x8 zv = *(const bf16x8*)&row[d8];
    const float* sc = scale + d8;
    bf16x8 o;
#pragma unroll
    for (int j = 0; j < 8; ++j) {
      bf16 hh = __float2bfloat16(vals[g * 8 + j] * inv * sc[j] * siluf(bf2f(zv[j])));
      o[j] = *(short*)&hh;
    }
    *(bf16x8*)&row[DINNER + d8] = o;
  }
}

// ---------------- launch ----------------
extern "C" void kernel_launch(void* const* d_in, const int* in_sizes, int n_in,
                              void* d_out, int out_size, void* d_ws, size_t ws_size,
                              hipStream_t stream) {
  const float* u       = (const float*)d_in[0];
  const float* Win     = (const float*)d_in[1];
  const float* cw      = (const float*)d_in[2];
  const float* cb      = (const float*)d_in[3];
  const float* A_log   = (const float*)d_in[4];
  const float* dt_bias = (const float*)d_in[5];
  const float* Dp      = (const float*)d_in[6];
  const float* nscale  = (const float*)d_in[7];
  const float* Wout    = (const float*)d_in[8];
  float* out = (float*)d_out;

  bf16* zx = (bf16*)d_ws;
  bf16* xc = zx + (size_t)MTOK * DPROJ;
  bf16* ub = xc;                                  // overlay: ub dead before xc written
  bf16* wT = xc + (size_t)MTOK * DINNER;
  bf16* Bmb = wT + (size_t)DPROJ_PAD * DMODEL;
  bf16* Cmb = Bmb + (size_t)MTOK * 64;
  float* cs = (float*)(Cmb + (size_t)MTOK * 64);
  bf16* st = (bf16*)d_out;                        // chunk states, 64 MiB

  cast_bf16_kernel<<<(MTOK * DMODEL) / (256 * 4), 256, 0, stream>>>(u, ub);
  transpose_cast_kernel<<<dim3(DPROJ_PAD / 32, DMODEL / 32), 256, 0, stream>>>(Win, wT, DPROJ, DMODEL);
  // 1a) in-projection z|x columns: N=8192, per-tile 16-wave kernel, grid 1024
  gemm_w16<bf16, DMODEL / 32><<<(2 * DINNER / 256) * (MTOK / 256), 1024, 0, stream>>>(
      ub, DMODEL, wT, DMODEL, zx, DPROJ, 2 * DINNER / 256);
  // 1b) in-projection BCdt columns: N=192, 32x128-tile high-TLP kernel, grid 512
  gemm_bcdt<bf16><<<dim3(2, MTOK / 32), 128, 0, stream>>>(
      ub, DMODEL, wT + (size_t)(2 * DINNER) * DMODEL, DMODEL,
      zx + 2 * DINNER, DPROJ, DMODEL, 192);
  transpose_cast_kernel<<<dim3(DMODEL / 32, DINNER / 32), 256, 0, stream>>>(Wout, wT, DMODEL, DINNER);
  conv_silu_kernel<<<(MTOK / 4) * 512 / 256, 256, 0, stream>>>(zx, cw, cb, xc);
  prep_cumsum_kernel<<<BATCH * NCHUNK, 256, 0, stream>>>(zx, A_log, dt_bias, Bmb, Cmb, cs);
  states_mfma<<<BATCH * NHEADS * NCHUNK, 256, 0, stream>>>(Bmb, xc, cs, st);
  scan_kernel<<<BATCH * NHEADS * 4, 256, 0, stream>>>(cs, st);
  chunk_out_mfma<<<BATCH * NHEADS * NCHUNK, 256, 0, stream>>>(Bmb, Cmb, xc, cs, st, Dp, zx);
  rmsnorm_gate_kernel<<<MTOK, 256, 0, stream>>>(zx, nscale);
  // 9) out-projection: period-2 16-wave kernel, float out, grid 256, KT=128
  gemm_w16p2<float, DINNER / 32><<<(DMODEL / 256) * (MTOK / 256), 1024, 0, stream>>>(
      zx + DINNER, DPROJ, wT, DINNER, out, DMODEL, DMODEL / 256);
}

// Round 18
// 627.315 us; speedup vs baseline: 1.1769x; 1.0126x over previous
//
#include <hip/hip_runtime.h>
#include <hip/hip_bf16.h>
#include <cstdint>
#include <cstddef>

// ---------------- problem constants ----------------
#define BATCH   2
#define SEQLEN  4096
#define DMODEL  2048
#define DINNER  4096
#define NHEADS  64
#define HEADDIM 64
#define DSTATE  64
#define CHUNK   64
#define NCHUNK  (SEQLEN/CHUNK)      // 64
#define DPROJ   8384
#define DPROJ_PAD 8448
#define MTOK    (BATCH*SEQLEN)      // 8192
#define RMS_EPS 1e-6f
#define CONVBLOCKS ((MTOK / 8) * 512 / 256)   // 2048

typedef __hip_bfloat16 bf16;
typedef __attribute__((ext_vector_type(8))) short bf16x8;
typedef __attribute__((ext_vector_type(4))) float f32x4;

__device__ __forceinline__ float siluf(float x) { return x / (1.f + expf(-x)); }
__device__ __forceinline__ float to_f(float x) { return x; }
__device__ __forceinline__ float to_f(bf16 x) { return __bfloat162float(x); }
__device__ __forceinline__ float bf2f(short s) { bf16 h; *(short*)&h = s; return __bfloat162float(h); }
__device__ __forceinline__ void from_f(float& d, float x) { d = x; }
__device__ __forceinline__ void from_f(bf16& d, float x) { d = __float2bfloat16(x); }

__device__ __forceinline__ void gload16(const void* g, void* l) {
  __builtin_amdgcn_global_load_lds(
      (const __attribute__((address_space(1))) void*)g,
      (__attribute__((address_space(3))) void*)l, 16, 0, 0);
}

// ---------------- gemm_w16: 256x256 tile, 16 waves, per-tile barrier ---------
template <typename TC, int KT>
__global__ __launch_bounds__(1024, 4) void gemm_w16(
    const bf16* __restrict__ A, int lda,
    const bf16* __restrict__ BT, int ldb,
    TC* __restrict__ C, int ldc, int gx) {
  __shared__ __align__(16) bf16 As[4 * 8192];
  __shared__ __align__(16) bf16 Bs[4 * 8192];
  const int tid  = threadIdx.x;
  const int lane = tid & 63;
  const int w    = tid >> 6;
  const int wm   = w >> 2;
  const int wn   = w & 3;
  const int lr   = lane & 15, lg = lane >> 4;
  const int fo   = 8 * (lg ^ ((lr >> 1) & 3));

  int nwg = gridDim.x;
  int bid = (int)blockIdx.x;
  int idx = (bid & 7) * (nwg >> 3) + (bid >> 3);
  int spos = idx % (8 * gx);
  const int m0 = ((idx / (8 * gx)) * 8 + (spos & 7)) * 256;
  const int n0 = (spos >> 3) * 256;

  const int srow = tid >> 2;
  const int ce   = 8 * ((tid & 3) ^ ((tid >> 3) & 3));
  const bf16* pA = A  + (size_t)(m0 + srow) * lda + ce;
  const bf16* pB = BT + (size_t)(n0 + srow) * ldb + ce;
  const int wofs = w * 512;
  const int aRd = (wm * 64 + lr) * 32 + fo;
  const int bRd = (wn * 64 + lr) * 32 + fo;

#define STAGE_A(kt) gload16(pA + ((kt) << 5), As + (((kt) & 3) << 13) + wofs)
#define STAGE_B(kt) gload16(pB + ((kt) << 5), Bs + (((kt) & 3) << 13) + wofs)

  f32x4 acc[4][4];
#pragma unroll
  for (int m = 0; m < 4; ++m)
#pragma unroll
    for (int n = 0; n < 4; ++n) acc[m][n] = (f32x4){0.f, 0.f, 0.f, 0.f};

#define KBODY(T, DOSTAGE, VMC) do {                                          \
    const bf16* Ab = As + (((T) & 3) << 13);                                 \
    const bf16* Bb = Bs + (((T) & 3) << 13);                                 \
    if (DOSTAGE) { STAGE_A((T) + 3); STAGE_B((T) + 3); }                     \
    bf16x8 bfv[4], af[4];                                                    \
    _Pragma("unroll")                                                        \
    for (int n = 0; n < 4; ++n) bfv[n] = *(const bf16x8*)&Bb[bRd + n * 512]; \
    _Pragma("unroll")                                                        \
    for (int m = 0; m < 4; ++m) af[m] = *(const bf16x8*)&Ab[aRd + m * 512];  \
    asm volatile("s_waitcnt lgkmcnt(0)" ::: "memory");                       \
    __builtin_amdgcn_sched_barrier(0);                                       \
    __builtin_amdgcn_s_setprio(1);                                           \
    _Pragma("unroll")                                                        \
    for (int m = 0; m < 4; ++m)                                              \
      _Pragma("unroll")                                                      \
      for (int n = 0; n < 4; ++n)                                            \
        acc[m][n] = __builtin_amdgcn_mfma_f32_16x16x32_bf16(af[m], bfv[n], acc[m][n], 0, 0, 0); \
    __builtin_amdgcn_s_setprio(0);                                           \
    asm volatile("s_waitcnt vmcnt(" #VMC ")" ::: "memory");                  \
    __builtin_amdgcn_s_barrier();                                            \
    __builtin_amdgcn_sched_barrier(0);                                       \
  } while (0)

  STAGE_A(0); STAGE_B(0); STAGE_A(1); STAGE_B(1); STAGE_A(2); STAGE_B(2);
  asm volatile("s_waitcnt vmcnt(4)" ::: "memory");
  __builtin_amdgcn_s_barrier();
  __builtin_amdgcn_sched_barrier(0);

#pragma unroll 4
  for (int t = 0; t < KT - 3; ++t) KBODY(t, true, 4);
  KBODY(KT - 3, false, 2);
  KBODY(KT - 2, false, 0);
  KBODY(KT - 1, false, 0);
#undef KBODY
#undef STAGE_A
#undef STAGE_B

  if constexpr (__is_same(TC, bf16)) {
    bf16* Ws = (w < 8 ? As : Bs) + (w & 7) * 4096;
#pragma unroll
    for (int m = 0; m < 4; ++m)
#pragma unroll
      for (int n = 0; n < 4; ++n)
#pragma unroll
        for (int reg = 0; reg < 4; ++reg) {
          int row = m * 16 + lg * 4 + reg;
          int slot = (n * 2 + (lr >> 3)) ^ (row & 7);
          Ws[row * 64 + slot * 8 + (lr & 7)] = __float2bfloat16(acc[m][n][reg]);
        }
    asm volatile("s_waitcnt lgkmcnt(0)" ::: "memory");
#pragma unroll
    for (int i = 0; i < 8; ++i) {
      int row = i * 8 + (lane >> 3);
      bf16x8 v = *(const bf16x8*)&Ws[row * 64 + ((lane & 7) ^ (lane >> 3)) * 8];
      int gcol = n0 + wn * 64 + (lane & 7) * 8;
      *(bf16x8*)&((bf16*)C)[(size_t)(m0 + wm * 64 + row) * ldc + gcol] = v;
    }
  } else {
#pragma unroll
    for (int m = 0; m < 4; ++m)
#pragma unroll
      for (int n = 0; n < 4; ++n) {
        int col = n0 + wn * 64 + n * 16 + lr;
        size_t rbase = (size_t)(m0 + wm * 64 + m * 16 + lg * 4);
#pragma unroll
        for (int reg = 0; reg < 4; ++reg)
          from_f(C[(rbase + reg) * ldc + col], acc[m][n][reg]);
      }
  }
}

// ---------------- gemm_w16p2: period-2 variant (best for KT=128 out-proj) ----
template <typename TC, int KT>
__global__ __launch_bounds__(1024, 4) void gemm_w16p2(
    const bf16* __restrict__ A, int lda,
    const bf16* __restrict__ BT, int ldb,
    TC* __restrict__ C, int ldc, int gx) {
  __shared__ __align__(16) bf16 As[4 * 8192];
  __shared__ __align__(16) bf16 Bs[4 * 8192];
  const int tid  = threadIdx.x;
  const int lane = tid & 63;
  const int w    = tid >> 6;
  const int wm   = w >> 2;
  const int wn   = w & 3;
  const int lr   = lane & 15, lg = lane >> 4;
  const int fo   = 8 * (lg ^ ((lr >> 1) & 3));

  int nwg = gridDim.x;
  int bid = (int)blockIdx.x;
  int idx = (bid & 7) * (nwg >> 3) + (bid >> 3);
  int spos = idx % (8 * gx);
  const int m0 = ((idx / (8 * gx)) * 8 + (spos & 7)) * 256;
  const int n0 = (spos >> 3) * 256;

  const int srow = tid >> 2;
  const int ce   = 8 * ((tid & 3) ^ ((tid >> 3) & 3));
  const bf16* pA = A  + (size_t)(m0 + srow) * lda + ce;
  const bf16* pB = BT + (size_t)(n0 + srow) * ldb + ce;
  const int wofs = w * 512;
  const int aRd = (wm * 64 + lr) * 32 + fo;
  const int bRd = (wn * 64 + lr) * 32 + fo;

#define STAGE_A(kt) gload16(pA + ((kt) << 5), As + (((kt) & 3) << 13) + wofs)
#define STAGE_B(kt) gload16(pB + ((kt) << 5), Bs + (((kt) & 3) << 13) + wofs)

  f32x4 acc[4][4];
#pragma unroll
  for (int m = 0; m < 4; ++m)
#pragma unroll
    for (int n = 0; n < 4; ++n) acc[m][n] = (f32x4){0.f, 0.f, 0.f, 0.f};

#define TILE(T) do {                                                         \
    const bf16* Ab = As + (((T) & 3) << 13);                                 \
    const bf16* Bb = Bs + (((T) & 3) << 13);                                 \
    bf16x8 bfv[4], af[4];                                                    \
    _Pragma("unroll")                                                        \
    for (int n = 0; n < 4; ++n) bfv[n] = *(const bf16x8*)&Bb[bRd + n * 512]; \
    _Pragma("unroll")                                                        \
    for (int m = 0; m < 4; ++m) af[m] = *(const bf16x8*)&Ab[aRd + m * 512];  \
    asm volatile("s_waitcnt lgkmcnt(0)" ::: "memory");                       \
    __builtin_amdgcn_sched_barrier(0);                                       \
    __builtin_amdgcn_s_setprio(1);                                           \
    _Pragma("unroll")                                                        \
    for (int m = 0; m < 4; ++m)                                              \
      _Pragma("unroll")                                                      \
      for (int n = 0; n < 4; ++n)                                            \
        acc[m][n] = __builtin_amdgcn_mfma_f32_16x16x32_bf16(af[m], bfv[n], acc[m][n], 0, 0, 0); \
    __builtin_amdgcn_s_setprio(0);                                           \
  } while (0)

#define PERIOD(P, DOSTAGE) do {                                              \
    if (DOSTAGE) { STAGE_A(2 * (P) + 2); STAGE_B(2 * (P) + 2);               \
                   STAGE_A(2 * (P) + 3); STAGE_B(2 * (P) + 3); }             \
    TILE(2 * (P));                                                           \
    TILE(2 * (P) + 1);                                                       \
    asm volatile("s_waitcnt vmcnt(0)" ::: "memory");                         \
    __builtin_amdgcn_s_barrier();                                            \
    __builtin_amdgcn_sched_barrier(0);                                       \
  } while (0)

  STAGE_A(0); STAGE_B(0); STAGE_A(1); STAGE_B(1);
  asm volatile("s_waitcnt vmcnt(0)" ::: "memory");
  __builtin_amdgcn_s_barrier();
  __builtin_amdgcn_sched_barrier(0);

  const int NP = KT / 2;
#pragma unroll 2
  for (int p = 0; p < NP - 1; ++p) PERIOD(p, true);
  PERIOD(NP - 1, false);
#undef PERIOD
#undef TILE
#undef STAGE_A
#undef STAGE_B

  if constexpr (__is_same(TC, bf16)) {
    bf16* Ws = (w < 8 ? As : Bs) + (w & 7) * 4096;
#pragma unroll
    for (int m = 0; m < 4; ++m)
#pragma unroll
      for (int n = 0; n < 4; ++n)
#pragma unroll
        for (int reg = 0; reg < 4; ++reg) {
          int row = m * 16 + lg * 4 + reg;
          int slot = (n * 2 + (lr >> 3)) ^ (row & 7);
          Ws[row * 64 + slot * 8 + (lr & 7)] = __float2bfloat16(acc[m][n][reg]);
        }
    asm volatile("s_waitcnt lgkmcnt(0)" ::: "memory");
#pragma unroll
    for (int i = 0; i < 8; ++i) {
      int row = i * 8 + (lane >> 3);
      bf16x8 v = *(const bf16x8*)&Ws[row * 64 + ((lane & 7) ^ (lane >> 3)) * 8];
      int gcol = n0 + wn * 64 + (lane & 7) * 8;
      *(bf16x8*)&((bf16*)C)[(size_t)(m0 + wm * 64 + row) * ldc + gcol] = v;
    }
  } else {
#pragma unroll
    for (int m = 0; m < 4; ++m)
#pragma unroll
      for (int n = 0; n < 4; ++n) {
        int col = n0 + wn * 64 + n * 16 + lr;
        size_t rbase = (size_t)(m0 + wm * 64 + m * 16 + lg * 4);
#pragma unroll
        for (int reg = 0; reg < 4; ++reg)
          from_f(C[(rbase + reg) * ldc + col], acc[m][n][reg]);
      }
  }
}

// ---------------- gemm_bcdt: 32x128 tile, 2 waves — narrow-N high-TLP GEMM ---
template <typename TC>
__global__ __launch_bounds__(128) void gemm_bcdt(
    const bf16* __restrict__ A, int lda,
    const bf16* __restrict__ BT, int ldb,
    TC* __restrict__ C, int ldc, int Kdim, int Nvalid) {
  __shared__ __align__(16) bf16 As[32 * 32];
  __shared__ __align__(16) bf16 Bs[128 * 32];
  const int tid  = threadIdx.x;
  const int lane = tid & 63;
  const int w    = tid >> 6;
  const int lr   = lane & 15, lg = lane >> 4;
  const int fo   = 8 * (lg ^ (lr & 3));
  const int m0 = blockIdx.y * 32;
  const int n0 = blockIdx.x * 128;

  const int srow = tid >> 2;
  const int ce   = 8 * ((tid & 3) ^ ((tid >> 2) & 3));
  const bf16* pA = A  + (size_t)(m0 + srow) * lda + ce;
  const bf16* pB = BT + (size_t)(n0 + srow) * ldb + ce;
  const int dof = w * 512;

  f32x4 acc[2][4];
#pragma unroll
  for (int m = 0; m < 2; ++m)
#pragma unroll
    for (int n = 0; n < 4; ++n) acc[m][n] = (f32x4){0.f, 0.f, 0.f, 0.f};

  for (int k0 = 0; k0 < Kdim; k0 += 32) {
    __syncthreads();
    gload16(pA + k0, As + dof);
    gload16(pB + k0,                    Bs + 0 * 1024 + dof);
    gload16(pB + (size_t)32 * ldb + k0, Bs + 1 * 1024 + dof);
    gload16(pB + (size_t)64 * ldb + k0, Bs + 2 * 1024 + dof);
    gload16(pB + (size_t)96 * ldb + k0, Bs + 3 * 1024 + dof);
    __syncthreads();
    bf16x8 af[2], bfr[4];
#pragma unroll
    for (int m = 0; m < 2; ++m)
      af[m] = *(const bf16x8*)&As[(m * 16 + lr) * 32 + fo];
#pragma unroll
    for (int n = 0; n < 4; ++n)
      bfr[n] = *(const bf16x8*)&Bs[(w * 64 + n * 16 + lr) * 32 + fo];
#pragma unroll
    for (int m = 0; m < 2; ++m)
#pragma unroll
      for (int n = 0; n < 4; ++n)
        acc[m][n] = __builtin_amdgcn_mfma_f32_16x16x32_bf16(af[m], bfr[n], acc[m][n], 0, 0, 0);
  }

#pragma unroll
  for (int m = 0; m < 2; ++m)
#pragma unroll
    for (int n = 0; n < 4; ++n) {
      int col = n0 + w * 64 + n * 16 + lr;
      if (col >= Nvalid) continue;
      size_t rbase = (size_t)(m0 + m * 16 + lg * 4);
#pragma unroll
      for (int reg = 0; reg < 4; ++reg)
        from_f(C[(rbase + reg) * ldc + col], acc[m][n][reg]);
    }
}

// ---------------- cast fp32 -> bf16 (4/thread) ----------------
__global__ __launch_bounds__(256) void cast_bf16_kernel(
    const float* __restrict__ x, bf16* __restrict__ y) {
  size_t i = ((size_t)blockIdx.x * 256 + threadIdx.x) * 4;
  float4 v = *(const float4*)(x + i);
  y[i + 0] = __float2bfloat16(v.x);
  y[i + 1] = __float2bfloat16(v.y);
  y[i + 2] = __float2bfloat16(v.z);
  y[i + 3] = __float2bfloat16(v.w);
}

// ---------------- transpose + cast: WT[Npad][K] = W[K][N]^T ----------------
__global__ __launch_bounds__(256) void transpose_cast_kernel(
    const float* __restrict__ W, bf16* __restrict__ WT, int N, int K) {
  __shared__ float t[32][33];
  int n0 = blockIdx.x * 32, k0 = blockIdx.y * 32;
  int tx = threadIdx.x & 31, ty = threadIdx.x >> 5;
#pragma unroll
  for (int i = 0; i < 4; ++i) {
    int n = n0 + tx;
    t[ty + i * 8][tx] = (n < N) ? W[(size_t)(k0 + ty + i * 8) * N + n] : 0.f;
  }
  __syncthreads();
#pragma unroll
  for (int i = 0; i < 4; ++i) {
    int nn = ty + i * 8;
    WT[(size_t)(n0 + nn) * K + k0 + tx] = __float2bfloat16(t[tx][nn]);
  }
}

// ---------------- merged: conv1d+SiLU (8 tok/thread) ∥ prep+cumsum -----------
// blocks [0, CONVBLOCKS): depthwise conv; blocks [CONVBLOCKS, +128): B/C
// elu+1 + log-decay + per-chunk cumsum (concurrent — both depend only on zx).
__global__ __launch_bounds__(256) void conv_prep_kernel(
    const bf16* __restrict__ zx, const float* __restrict__ cw,
    const float* __restrict__ cb, bf16* __restrict__ xc,
    const float* __restrict__ A_log, const float* __restrict__ dt_bias,
    bf16* __restrict__ Bmb, bf16* __restrict__ Cmb, float* __restrict__ cs) {
  int bid = blockIdx.x;
  int tid = threadIdx.x;
  if (bid < CONVBLOCKS) {
    // ---- conv: 8 tokens/thread, 11-row sliding window ----
    int idx = bid * 256 + tid;        // over (MTOK/8) * 512
    int d8 = (idx & 511) * 8;
    int g = idx >> 9;
    int m0 = g * 8;
    int l0 = m0 & (SEQLEN - 1);
    int b = m0 >> 12;
    bf16x8 rows[11];
    bf16x8 zvec;
#pragma unroll
    for (int j = 0; j < 8; ++j) zvec[j] = 0;
#pragma unroll
    for (int r = 0; r < 11; ++r) {
      int li = l0 - 3 + r;
      rows[r] = (li >= 0)
          ? *(const bf16x8*)&zx[(size_t)(b * SEQLEN + li) * DPROJ + DINNER + d8]
          : zvec;
    }
    float cwv[4][8], cbv[8];
#pragma unroll
    for (int k = 0; k < 4; ++k) {
      float4 a = *(const float4*)(cw + k * DINNER + d8);
      float4 bb = *(const float4*)(cw + k * DINNER + d8 + 4);
      cwv[k][0] = a.x; cwv[k][1] = a.y; cwv[k][2] = a.z; cwv[k][3] = a.w;
      cwv[k][4] = bb.x; cwv[k][5] = bb.y; cwv[k][6] = bb.z; cwv[k][7] = bb.w;
    }
    {
      float4 a = *(const float4*)(cb + d8);
      float4 bb = *(const float4*)(cb + d8 + 4);
      cbv[0] = a.x; cbv[1] = a.y; cbv[2] = a.z; cbv[3] = a.w;
      cbv[4] = bb.x; cbv[5] = bb.y; cbv[6] = bb.z; cbv[7] = bb.w;
    }
#pragma unroll
    for (int j = 0; j < 8; ++j) {
      float acc[8];
#pragma unroll
      for (int e = 0; e < 8; ++e) acc[e] = cbv[e];
#pragma unroll
      for (int k = 0; k < 4; ++k)
#pragma unroll
        for (int e = 0; e < 8; ++e) acc[e] += bf2f(rows[j + k][e]) * cwv[k][e];
      bf16x8 o;
#pragma unroll
      for (int e = 0; e < 8; ++e) { bf16 h = __float2bfloat16(siluf(acc[e])); o[e] = *(short*)&h; }
      *(bf16x8*)&xc[(size_t)(m0 + j) * DINNER + d8] = o;
    }
  } else {
    // ---- prep + cumsum (one block per (b,c)) ----
    int bid2 = bid - CONVBLOCKS;      // b*64 + c
    int c = bid2 & 63, b = bid2 >> 6;
    int m0 = b * SEQLEN + c * CHUNK;
    int s = tid >> 2, grp = (tid & 3) * 16;
    __shared__ float laT[64 * 65];
    __shared__ float segs[4][64];
    const bf16* row = zx + (size_t)(m0 + s) * DPROJ + 2 * DINNER;
    {
      union { bf16x8 v[2]; bf16 hh[16]; } u, o;
      u.v[0] = *(const bf16x8*)&row[grp];
      u.v[1] = *(const bf16x8*)&row[grp + 8];
#pragma unroll
      for (int i = 0; i < 16; ++i) {
        float bv = to_f(u.hh[i]);
        from_f(o.hh[i], bv > 0.f ? bv + 1.f : expf(bv));
      }
      *(bf16x8*)&Bmb[(size_t)(m0 + s) * 64 + grp] = o.v[0];
      *(bf16x8*)&Bmb[(size_t)(m0 + s) * 64 + grp + 8] = o.v[1];
      u.v[0] = *(const bf16x8*)&row[64 + grp];
      u.v[1] = *(const bf16x8*)&row[64 + grp + 8];
#pragma unroll
      for (int i = 0; i < 16; ++i) {
        float cv = to_f(u.hh[i]);
        from_f(o.hh[i], cv > 0.f ? cv + 1.f : expf(cv));
      }
      *(bf16x8*)&Cmb[(size_t)(m0 + s) * 64 + grp] = o.v[0];
      *(bf16x8*)&Cmb[(size_t)(m0 + s) * 64 + grp + 8] = o.v[1];
      u.v[0] = *(const bf16x8*)&row[128 + grp];
      u.v[1] = *(const bf16x8*)&row[128 + grp + 8];
#pragma unroll
      for (int i = 0; i < 16; ++i) {
        int j = grp + i;
        float dtl = to_f(u.hh[i]) + dt_bias[j];
        float dt = dtl > 20.f ? dtl : log1pf(expf(dtl));
        laT[j * 65 + s] = -dt * expf(A_log[j]);
      }
    }
    __syncthreads();
    int j = tid & 63, sg = tid >> 6;
    float p = 0.f;
#pragma unroll
    for (int i = 0; i < 16; ++i) p += laT[j * 65 + sg * 16 + i];
    segs[sg][j] = p;
    __syncthreads();
    float off = (sg > 0 ? segs[0][j] : 0.f) + (sg > 1 ? segs[1][j] : 0.f) +
                (sg > 2 ? segs[2][j] : 0.f);
    float acc = off;
#pragma unroll
    for (int i = 0; i < 16; ++i) {
      acc += laT[j * 65 + sg * 16 + i];
      cs[(size_t)(m0 + sg * 16 + i) * 64 + j] = acc;
    }
  }
}

// ---------------- per-chunk state via MFMA: stT[p][n] = sum_s v[s][p]*ksc[s][n] ----------------
__global__ __launch_bounds__(256) void states_mfma(
    const bf16* __restrict__ Bmb, const bf16* __restrict__ xc,
    const float* __restrict__ cs, bf16* __restrict__ st) {
  int bid = blockIdx.x;
  int c = bid & 63, h = (bid >> 6) & 63, b = bid >> 12;
  int m0 = b * SEQLEN + c * CHUNK;
  int tid = threadIdx.x, lane = tid & 63, w = tid >> 6;
  int lr = lane & 15, lg = lane >> 4;
  __shared__ bf16 vT[64 * 72];
  __shared__ bf16 kT[64 * 72];
  int s4 = tid >> 2, c16 = (tid & 3) * 16;
  float cstot = cs[(size_t)(m0 + 63) * 64 + h];
  float ws = expf(cstot - cs[(size_t)(m0 + s4) * 64 + h]);
  {
    union { bf16x8 v[2]; bf16 hh[16]; } u;
    const bf16x8* pv = (const bf16x8*)&xc[(size_t)(m0 + s4) * DINNER + h * 64 + c16];
    u.v[0] = pv[0]; u.v[1] = pv[1];
#pragma unroll
    for (int i = 0; i < 16; ++i) vT[(c16 + i) * 72 + s4] = u.hh[i];
    const bf16x8* pk = (const bf16x8*)&Bmb[(size_t)(m0 + s4) * 64 + c16];
    u.v[0] = pk[0]; u.v[1] = pk[1];
#pragma unroll
    for (int i = 0; i < 16; ++i) kT[(c16 + i) * 72 + s4] = __float2bfloat16(to_f(u.hh[i]) * ws);
  }
  __syncthreads();
  f32x4 acc[4];
#pragma unroll
  for (int ct = 0; ct < 4; ++ct) acc[ct] = (f32x4){0.f, 0.f, 0.f, 0.f};
#pragma unroll
  for (int ks = 0; ks < 2; ++ks) {
    bf16x8 af = *(const bf16x8*)&vT[(w * 16 + lr) * 72 + ks * 32 + lg * 8];
#pragma unroll
    for (int ct = 0; ct < 4; ++ct) {
      bf16x8 bf_ = *(const bf16x8*)&kT[(ct * 16 + lr) * 72 + ks * 32 + lg * 8];
      acc[ct] = __builtin_amdgcn_mfma_f32_16x16x32_bf16(af, bf_, acc[ct], 0, 0, 0);
    }
  }
  size_t ob = (((size_t)(b * NHEADS + h)) * NCHUNK + c) * 4096;
#pragma unroll
  for (int ct = 0; ct < 4; ++ct) {
    int n = ct * 16 + lr;
#pragma unroll
    for (int r = 0; r < 4; ++r) {
      int p = w * 16 + lg * 4 + r;
      from_f(st[ob + (size_t)p * 64 + n], acc[ct][r]);
    }
  }
}

// ---------------- sequential scan over chunks; dec[] staged, ring-4 prefetch --
__global__ __launch_bounds__(256) void scan_kernel(
    const float* __restrict__ cs, bf16* __restrict__ st) {
  int bid = blockIdx.x;
  int bh = bid >> 2, qq = bid & 3;
  int b = bh >> 6, h = bh & 63;
  int tid = threadIdx.x;
  __shared__ float dec[64];
  if (tid < 64)
    dec[tid] = expf(cs[(size_t)(b * SEQLEN + tid * CHUNK + 63) * 64 + h]);
  int e0 = qq * 1024 + tid * 4;
  float hr[4] = {0.f, 0.f, 0.f, 0.f};
  size_t base = (size_t)bh * NCHUNK * 4096;
  typedef __attribute__((ext_vector_type(4))) short bf16x4;
  union U { bf16x4 v; bf16 hh[4]; };
  U buf[4];
  buf[0].v = *(bf16x4*)(st + base + 0 * 4096 + e0);
  buf[1].v = *(bf16x4*)(st + base + 1 * 4096 + e0);
  buf[2].v = *(bf16x4*)(st + base + 2 * 4096 + e0);
  __syncthreads();
#pragma unroll 4
  for (int c = 0; c < NCHUNK; ++c) {
    if (c + 3 < NCHUNK)
      buf[(c + 3) & 3].v = *(bf16x4*)(st + base + (size_t)(c + 3) * 4096 + e0);
    float d = dec[c];
    U out;
#pragma unroll
    for (int i = 0; i < 4; ++i) {
      float sv = to_f(buf[c & 3].hh[i]);
      from_f(out.hh[i], hr[i]);
      hr[i] = d * hr[i] + sv;
    }
    *(bf16x4*)(st + base + (size_t)c * 4096 + e0) = out.v;
  }
}

// ---------------- per-chunk output via MFMA ----------------
__global__ __launch_bounds__(256) void chunk_out_mfma(
    const bf16* __restrict__ Bmb, const bf16* __restrict__ Cmb,
    const bf16* __restrict__ xc, const float* __restrict__ cs,
    const bf16* __restrict__ st, const float* __restrict__ Dp,
    bf16* __restrict__ zx) {
  int bid = blockIdx.x;
  int c = bid & 63, h = (bid >> 6) & 63, b = bid >> 12;
  int m0 = b * SEQLEN + c * CHUNK;
  int tid = threadIdx.x, lane = tid & 63, w = tid >> 6;
  int lr = lane & 15, lg = lane >> 4;
  __shared__ bf16 qL[64 * 72];
  __shared__ bf16 kL[64 * 72];
  __shared__ bf16 A2[64 * 136];
  __shared__ bf16 B2[64 * 136];
  __shared__ float csl[64];
  int s4 = tid >> 2, c16 = (tid & 3) * 16;

  if (tid < 64) csl[tid] = cs[(size_t)(m0 + tid) * 64 + h];
  {
    const bf16x8* pq = (const bf16x8*)&Cmb[(size_t)(m0 + s4) * 64 + c16];
    *(bf16x8*)&qL[s4 * 72 + c16] = pq[0];
    *(bf16x8*)&qL[s4 * 72 + c16 + 8] = pq[1];
    const bf16x8* pk = (const bf16x8*)&Bmb[(size_t)(m0 + s4) * 64 + c16];
    *(bf16x8*)&kL[s4 * 72 + c16] = pk[0];
    *(bf16x8*)&kL[s4 * 72 + c16 + 8] = pk[1];
  }
  {
    union { bf16x8 v[2]; bf16 hh[16]; } u;
    const bf16x8* pv = (const bf16x8*)&xc[(size_t)(m0 + s4) * DINNER + h * 64 + c16];
    u.v[0] = pv[0]; u.v[1] = pv[1];
#pragma unroll
    for (int i = 0; i < 16; ++i) B2[(c16 + i) * 136 + s4] = u.hh[i];
  }
  {
    size_t hb = (((size_t)(b * NHEADS + h)) * NCHUNK + c) * 4096;
    const bf16x8* ph = (const bf16x8*)&st[hb + (size_t)s4 * 64 + c16];
    *(bf16x8*)&B2[s4 * 136 + 64 + c16] = ph[0];
    *(bf16x8*)&B2[s4 * 136 + 64 + c16 + 8] = ph[1];
  }
  __syncthreads();

  f32x4 acc1[4];
#pragma unroll
  for (int ct = 0; ct < 4; ++ct) acc1[ct] = (f32x4){0.f, 0.f, 0.f, 0.f};
#pragma unroll
  for (int ks = 0; ks < 2; ++ks) {
    bf16x8 af = *(const bf16x8*)&qL[(w * 16 + lr) * 72 + ks * 32 + lg * 8];
#pragma unroll
    for (int ct = 0; ct < 4; ++ct) {
      bf16x8 bf_ = *(const bf16x8*)&kL[(ct * 16 + lr) * 72 + ks * 32 + lg * 8];
      acc1[ct] = __builtin_amdgcn_mfma_f32_16x16x32_bf16(af, bf_, acc1[ct], 0, 0, 0);
    }
  }
  {
    float es = expf(csl[s4]);
    union { bf16x8 v[2]; bf16 hh[16]; } u;
    const bf16x8* pq = (const bf16x8*)&qL[s4 * 72 + c16];
    u.v[0] = pq[0]; u.v[1] = pq[1];
#pragma unroll
    for (int i = 0; i < 16; ++i) u.hh[i] = __float2bfloat16(to_f(u.hh[i]) * es);
    *(bf16x8*)&A2[s4 * 136 + 64 + c16] = u.v[0];
    *(bf16x8*)&A2[s4 * 136 + 64 + c16 + 8] = u.v[1];
  }
#pragma unroll
  for (int ct = 0; ct < 4; ++ct) {
    int t = ct * 16 + lr;
#pragma unroll
    for (int r = 0; r < 4; ++r) {
      int s = w * 16 + lg * 4 + r;
      float val = (t <= s) ? acc1[ct][r] * expf(csl[s] - csl[t]) : 0.f;
      A2[s * 136 + t] = __float2bfloat16(val);
    }
  }
  __syncthreads();

  float Dh = Dp[h];
  f32x4 acc2[4];
#pragma unroll
  for (int ct = 0; ct < 4; ++ct) {
    int p = ct * 16 + lr;
#pragma unroll
    for (int r = 0; r < 4; ++r)
      acc2[ct][r] = Dh * to_f(B2[p * 136 + (w * 16 + lg * 4 + r)]);
  }
#pragma unroll
  for (int ks = 0; ks < 4; ++ks) {
    bf16x8 af = *(const bf16x8*)&A2[(w * 16 + lr) * 136 + ks * 32 + lg * 8];
#pragma unroll
    for (int ct = 0; ct < 4; ++ct) {
      bf16x8 bf_ = *(const bf16x8*)&B2[(ct * 16 + lr) * 136 + ks * 32 + lg * 8];
      acc2[ct] = __builtin_amdgcn_mfma_f32_16x16x32_bf16(af, bf_, acc2[ct], 0, 0, 0);
    }
  }
  __syncthreads();
#pragma unroll
  for (int ct = 0; ct < 4; ++ct) {
    int p = ct * 16 + lr;
#pragma unroll
    for (int r = 0; r < 4; ++r)
      qL[(w * 16 + lg * 4 + r) * 72 + p] = __float2bfloat16(acc2[ct][r]);
  }
  __syncthreads();
  {
    const bf16x8* py = (const bf16x8*)&qL[s4 * 72 + c16];
    bf16x8* pg = (bf16x8*)&zx[(size_t)(m0 + s4) * DPROJ + DINNER + h * 64 + c16];
    pg[0] = py[0]; pg[1] = py[1];
  }
}

// ---------------- RMSNorm over 4096 + silu(z) gate, bf16x8 ----------------
__global__ __launch_bounds__(256) void rmsnorm_gate_kernel(
    bf16* __restrict__ zx, const float* __restrict__ scale) {
  int m = blockIdx.x;
  int tid = threadIdx.x;
  bf16* row = zx + (size_t)m * DPROJ;
  float vals[16];
  float ss = 0.f;
#pragma unroll
  for (int g = 0; g < 2; ++g) {
    int d8 = (tid + g * 256) * 8;
    bf16x8 yv = *(const bf16x8*)&row[DINNER + d8];
#pragma unroll
    for (int j = 0; j < 8; ++j) {
      float y = bf2f(yv[j]);
      vals[g * 8 + j] = y;
      ss += y * y;
    }
  }
#pragma unroll
  for (int off = 32; off > 0; off >>= 1) ss += __shfl_down(ss, off, 64);
  __shared__ float red[4];
  if ((tid & 63) == 0) red[tid >> 6] = ss;
  __syncthreads();
  float tot = red[0] + red[1] + red[2] + red[3];
  float inv = rsqrtf(tot / (float)DINNER + RMS_EPS);
#pragma unroll
  for (int g = 0; g < 2; ++g) {
    int d8 = (tid + g * 256) * 8;
    bf16x8 zv = *(const bf16x8*)&row[d8];
    const float* sc = scale + d8;
    bf16x8 o;
#pragma unroll
    for (int j = 0; j < 8; ++j) {
      bf16 hh = __float2bfloat16(vals[g * 8 + j] * inv * sc[j] * siluf(bf2f(zv[j])));
      o[j] = *(short*)&hh;
    }
    *(bf16x8*)&row[DINNER + d8] = o;
  }
}

// ---------------- launch ----------------
extern "C" void kernel_launch(void* const* d_in, const int* in_sizes, int n_in,
                              void* d_out, int out_size, void* d_ws, size_t ws_size,
                              hipStream_t stream) {
  const float* u       = (const float*)d_in[0];
  const float* Win     = (const float*)d_in[1];
  const float* cw      = (const float*)d_in[2];
  const float* cb      = (const float*)d_in[3];
  const float* A_log   = (const float*)d_in[4];
  const float* dt_bias = (const float*)d_in[5];
  const float* Dp      = (const float*)d_in[6];
  const float* nscale  = (const float*)d_in[7];
  const float* Wout    = (const float*)d_in[8];
  float* out = (float*)d_out;

  bf16* zx = (bf16*)d_ws;
  bf16* xc = zx + (size_t)MTOK * DPROJ;
  bf16* ub = xc;                                  // overlay: ub dead before xc written
  bf16* wT = xc + (size_t)MTOK * DINNER;
  bf16* Bmb = wT + (size_t)DPROJ_PAD * DMODEL;
  bf16* Cmb = Bmb + (size_t)MTOK * 64;
  float* cs = (float*)(Cmb + (size_t)MTOK * 64);
  bf16* st = (bf16*)d_out;                        // chunk states, 64 MiB

  cast_bf16_kernel<<<(MTOK * DMODEL) / (256 * 4), 256, 0, stream>>>(u, ub);
  transpose_cast_kernel<<<dim3(DPROJ_PAD / 32, DMODEL / 32), 256, 0, stream>>>(Win, wT, DPROJ, DMODEL);
  // 1a) in-projection z|x columns: N=8192, per-tile 16-wave kernel, grid 1024
  gemm_w16<bf16, DMODEL / 32><<<(2 * DINNER / 256) * (MTOK / 256), 1024, 0, stream>>>(
      ub, DMODEL, wT, DMODEL, zx, DPROJ, 2 * DINNER / 256);
  // 1b) in-projection BCdt columns: N=192, 32x128-tile high-TLP kernel
  gemm_bcdt<bf16><<<dim3(2, MTOK / 32), 128, 0, stream>>>(
      ub, DMODEL, wT + (size_t)(2 * DINNER) * DMODEL, DMODEL,
      zx + 2 * DINNER, DPROJ, DMODEL, 192);
  transpose_cast_kernel<<<dim3(DMODEL / 32, DINNER / 32), 256, 0, stream>>>(Wout, wT, DMODEL, DINNER);
  // 2+3) merged conv(8 tok/thr) ∥ prep+cumsum
  conv_prep_kernel<<<CONVBLOCKS + BATCH * NCHUNK, 256, 0, stream>>>(
      zx, cw, cb, xc, A_log, dt_bias, Bmb, Cmb, cs);
  states_mfma<<<BATCH * NHEADS * NCHUNK, 256, 0, stream>>>(Bmb, xc, cs, st);
  scan_kernel<<<BATCH * NHEADS * 4, 256, 0, stream>>>(cs, st);
  chunk_out_mfma<<<BATCH * NHEADS * NCHUNK, 256, 0, stream>>>(Bmb, Cmb, xc, cs, st, Dp, zx);
  rmsnorm_gate_kernel<<<MTOK, 256, 0, stream>>>(zx, nscale);
  // 9) out-projection: period-2 16-wave kernel, float out, grid 256, KT=128
  gemm_w16p2<float, DINNER / 32><<<(DMODEL / 256) * (MTOK / 256), 1024, 0, stream>>>(
      zx + DINNER, DPROJ, wT, DINNER, out, DMODEL, DMODEL / 256);
}